// Round 4
// baseline (1493.953 us; speedup 1.0000x reference)
//
#include <hip/hip_runtime.h>
#include <hip/hip_bf16.h>
#include <math.h>

#define R_TOTAL 64000   // B*G*T*N
#define D 256
#define DFF 1024
#define MDIM 128
#define NB 500
#define TT 16
#define NTRACK 4000
#define NBLK 500        // R_TOTAL / 128

typedef __attribute__((ext_vector_type(8))) short bf8_t;   // 8 bf16 in 4 VGPR
typedef __attribute__((ext_vector_type(4))) float f4_t;    // MFMA acc

__device__ __forceinline__ float gelu_fast(float x) {
    // tanh-gelu == x * sigmoid(1.59576912(x+0.044715x^3))
    float z = 1.5957691216057308f * (x + 0.044715f * x * x * x);
    return x / (1.0f + __expf(-z));
}

__device__ __forceinline__ float gelu_f(float x) {   // fallback path (tanhf)
    float x3 = x * x * x;
    float t = tanhf(0.7978845608028654f * (x + 0.044715f * x3));
    return 0.5f * x * (1.0f + t);
}

// ===========================================================================
// ======================  FAST PATH: bf16x3-split MFMA  =====================
// ===========================================================================
// Weight tiles: [colblk][kstep][plane2][n128][k32] bf16 (row-major in k).
//   A wave's B-fragment load = contiguous 16B per lane; whole wave covers a
//   contiguous 1KB — L2-resident, no LDS staging for B at all.
// A (fp32) split hi/lo on the fly into LDS [plane][128][32] bf16 (64B rows):
//   stage-write and frag-read are both bijections onto contiguous regions →
//   bank-conflict-free.

enum { EP_GELU = 0, EP_RELU = 1, EP_BIAS = 2, EP_BIASRES = 3, EP_MASK = 4 };

template<int MODE>
__global__ __launch_bounds__(256, 3)
void gemm_split(const float* __restrict__ A1, int K1,
                const float* __restrict__ A2, int K2w,
                const ushort* __restrict__ Wt,
                const float* __restrict__ bias,
                const float* __restrict__ res,
                const int* __restrict__ mask,
                float* __restrict__ out, int N, int nk,
                int aBase, int oBase)
{
    __shared__ __align__(16) ushort sA[2][2][128][32];   // [buf][plane][r][k] 32KB

    const int tid = threadIdx.x;
    const int lane = tid & 63, wid = tid >> 6;
    const int wr = wid >> 1, wc = wid & 1;
    const int colblk = blockIdx.y;
    const int row0A = (aBase + blockIdx.x) * 128;
    const int row0O = (oBase + blockIdx.x) * 128;
    const int lm = lane & 15, lg = lane >> 4;

    f4_t acc[4][4];
#pragma unroll
    for (int i = 0; i < 4; ++i)
#pragma unroll
        for (int j = 0; j < 4; ++j) acc[i][j] = (f4_t)0.f;

    auto stageA = [&](int ks, int buf) {
        const int part = tid & 7;      // k-quad within 32
        const int rl = tid >> 3;       // 0..31
        const int k0 = ks * 32;
#pragma unroll
        for (int p = 0; p < 4; ++p) {
            int r = rl + p * 32;
            float4 v;
            if (k0 < K1) {
                v = *(const float4*)(A1 + (size_t)(row0A + r) * K1 + k0 + part * 4);
            } else {
                int kc = k0 - K1 + part * 4;
                if (kc < K2w)
                    v = *(const float4*)(A2 + (size_t)(row0A + r) * K2w + kc);
                else
                    v = float4{0.f, 0.f, 0.f, 0.f};
            }
            union { __hip_bfloat162 b2[2]; uint2 u; } H, L;
            H.b2[0] = __float22bfloat162_rn(float2{v.x, v.y});
            H.b2[1] = __float22bfloat162_rn(float2{v.z, v.w});
            float r0 = v.x - __bfloat162float(H.b2[0].x);
            float r1 = v.y - __bfloat162float(H.b2[0].y);
            float r2 = v.z - __bfloat162float(H.b2[1].x);
            float r3 = v.w - __bfloat162float(H.b2[1].y);
            L.b2[0] = __float22bfloat162_rn(float2{r0, r1});
            L.b2[1] = __float22bfloat162_rn(float2{r2, r3});
            *(uint2*)&sA[buf][0][r][part * 4] = H.u;
            *(uint2*)&sA[buf][1][r][part * 4] = L.u;
        }
    };

    auto compute = [&](int buf, int ks) {
        // B fragments straight from global (tiled, L2-resident)
        const ushort* wb = Wt + (((size_t)(colblk * nk + ks)) * 2) * 4096
                              + (wc * 64 + lm) * 32 + lg * 8;
        bf8_t Bh[4], Bl[4], Ah[4], Al[4];
#pragma unroll
        for (int ct = 0; ct < 4; ++ct) {
            Bh[ct] = *(const bf8_t*)(wb + ct * 512);          // plane 0
            Bl[ct] = *(const bf8_t*)(wb + 4096 + ct * 512);   // plane 1
        }
#pragma unroll
        for (int rt = 0; rt < 4; ++rt) {
            int r = wr * 64 + rt * 16 + lm;
            Ah[rt] = *(const bf8_t*)&sA[buf][0][r][lg * 8];
            Al[rt] = *(const bf8_t*)&sA[buf][1][r][lg * 8];
        }
#pragma unroll
        for (int rt = 0; rt < 4; ++rt)
#pragma unroll
            for (int ct = 0; ct < 4; ++ct) {
                acc[rt][ct] = __builtin_amdgcn_mfma_f32_16x16x32_bf16(Ah[rt], Bh[ct], acc[rt][ct], 0, 0, 0);
                acc[rt][ct] = __builtin_amdgcn_mfma_f32_16x16x32_bf16(Ah[rt], Bl[ct], acc[rt][ct], 0, 0, 0);
                acc[rt][ct] = __builtin_amdgcn_mfma_f32_16x16x32_bf16(Al[rt], Bh[ct], acc[rt][ct], 0, 0, 0);
            }
    };

    stageA(0, 0);
    __syncthreads();
    for (int ks = 0; ks < nk; ++ks) {
        int cur = ks & 1;
        if (ks + 1 < nk) stageA(ks + 1, cur ^ 1);
        compute(cur, ks);
        __syncthreads();
    }

    // Epilogue: C/D layout col=lane&15, row=(lane>>4)*4+reg  [m89-verified]
#pragma unroll
    for (int ct = 0; ct < 4; ++ct) {
        int col = colblk * 128 + wc * 64 + ct * 16 + lm;
        float bv = bias[col];
#pragma unroll
        for (int rt = 0; rt < 4; ++rt) {
#pragma unroll
            for (int rg = 0; rg < 4; ++rg) {
                int row = row0O + wr * 64 + rt * 16 + lg * 4 + rg;
                float v = acc[rt][ct][rg] + bv;
                if (MODE == EP_GELU)    v = gelu_fast(v);
                else if (MODE == EP_RELU) v = fmaxf(v, 0.f);
                else if (MODE == EP_BIASRES) v += res[(size_t)row * N + col];
                else if (MODE == EP_MASK)    v *= (mask[row] != 0) ? 1.0f : 0.0f;
                out[(size_t)row * N + col] = v;
            }
        }
    }
}

// --------------------- weight split+tile prep (one launch) -----------------
struct WPrepAll {
    const float* src[9];
    ushort* dst[9];
    int K[9], Kpad[9], logN[9];
    int base[10];
};

__global__ __launch_bounds__(256)
void prep_weights(WPrepAll P)
{
    int idx = blockIdx.x * 256 + threadIdx.x;
    int total = P.base[9];
    for (; idx < total; idx += gridDim.x * 256) {
        int d = 0;
        while (idx >= P.base[d + 1]) ++d;
        int local = idx - P.base[d];
        int N = 1 << P.logN[d];
        int n = local & (N - 1);
        int k = local >> P.logN[d];
        float w = (k < P.K[d]) ? P.src[d][(size_t)k * N + n] : 0.0f;
        __hip_bfloat16 hb = __float2bfloat16(w);
        float hf = __bfloat162float(hb);
        __hip_bfloat16 lb = __float2bfloat16(w - hf);
        int colblk = n >> 7, nloc = n & 127;
        int kstep = k >> 5, kk = k & 31;
        int nks = P.Kpad[d] >> 5;
        size_t off = (((size_t)(colblk * nks + kstep)) * 2) * 4096 + (size_t)nloc * 32 + kk;
        P.dst[d][off] = __hip_bfloat16_raw(hb).x;
        P.dst[d][off + 4096] = __hip_bfloat16_raw(lb).x;
    }
}

// --------------------- box8 = [boxes(4) | vel(4)] --------------------------
__global__ __launch_bounds__(256)
void prep_box8(const float* __restrict__ boxes, float* __restrict__ box8)
{
    int idx = blockIdx.x * 256 + threadIdx.x;
    if (idx >= R_TOTAL * 8) return;
    int row = idx >> 3, c = idx & 7;
    float v;
    if (c < 4) {
        v = boxes[(size_t)row * 4 + c];
    } else {
        int tt = (row / NB) % TT;
        int prev = (tt == 0) ? row : row - NB;
        int j = c - 4;
        v = boxes[(size_t)row * 4 + j] - boxes[(size_t)prev * 4 + j];
    }
    box8[(size_t)row * 8 + c] = v;
}

// ---------------------------------------------------------------------------
__global__ __launch_bounds__(256)
void ln_kernel(const float* __restrict__ X, const float* __restrict__ g,
               const float* __restrict__ b, float* __restrict__ Y)
{
    const int lane = threadIdx.x & 63;
    const int wave = threadIdx.x >> 6;
    const size_t row = (size_t)blockIdx.x * 4 + wave;
    float4 v = reinterpret_cast<const float4*>(X + row * D)[lane];
    float s = v.x + v.y + v.z + v.w;
#pragma unroll
    for (int m = 32; m >= 1; m >>= 1) s += __shfl_xor(s, m, 64);
    float mu = s * (1.0f / 256.0f);
    float4 d = {v.x - mu, v.y - mu, v.z - mu, v.w - mu};
    float q = d.x * d.x + d.y * d.y + d.z * d.z + d.w * d.w;
#pragma unroll
    for (int m = 32; m >= 1; m >>= 1) q += __shfl_xor(q, m, 64);
    float var = q * (1.0f / 256.0f);
    float sc = 1.0f / sqrtf(var + 1e-5f);
    float4 gv = reinterpret_cast<const float4*>(g)[lane];
    float4 bv = reinterpret_cast<const float4*>(b)[lane];
    float4 o = {d.x * sc * gv.x + bv.x, d.y * sc * gv.y + bv.y,
                d.z * sc * gv.z + bv.z, d.w * sc * gv.w + bv.w};
    reinterpret_cast<float4*>(Y + row * D)[lane] = o;
}

// ---------------------------------------------------------------------------
__global__ __launch_bounds__(256)
void kalman_kernel(const float* __restrict__ boxes, const int* __restrict__ masks,
                   float* __restrict__ st, float* __restrict__ cov)
{
    int i = blockIdx.x * blockDim.x + threadIdx.x;
    if (i >= NTRACK) return;
    int n = i % NB;
    int bg = i / NB;
    size_t rowlast = ((size_t)bg * TT + (TT - 1)) * NB + n;

    float z[4];
#pragma unroll
    for (int j = 0; j < 4; ++j) z[j] = boxes[rowlast * 4 + j];
    int mask = masks[rowlast];

#pragma unroll
    for (int j = 0; j < 4; ++j) st[(size_t)i * 8 + j] = z[j];
#pragma unroll
    for (int j = 4; j < 8; ++j) st[(size_t)i * 8 + j] = 0.0f;

    float C[8][8];
    if (mask != 0) {
#pragma unroll
        for (int a = 0; a < 8; ++a)
#pragma unroll
            for (int b = 0; b < 8; ++b) C[a][b] = (a == b) ? 1.0f : 0.0f;
    } else {
        float Pp[8][8];
#pragma unroll
        for (int a = 0; a < 8; ++a) {
#pragma unroll
            for (int b = 0; b < 8; ++b) {
                float s = 0.f;
#pragma unroll
                for (int k = 0; k < 8; ++k) {
                    float Fa = (a == k ? 1.f : 0.f) + ((a < 4 && k == a + 4) ? 1.f : 0.f);
                    float Fb = (b == k ? 1.f : 0.f) + ((b < 4 && k == b + 4) ? 1.f : 0.f);
                    s = fmaf(Fa, Fb, s);
                }
                Pp[a][b] = s + ((a == b) ? 0.01f : 0.0f);
            }
        }
        float S[4];
#pragma unroll
        for (int j = 0; j < 4; ++j) S[j] = Pp[j][j] + 0.1f;
        float K[8][4];
#pragma unroll
        for (int a = 0; a < 8; ++a)
#pragma unroll
            for (int j = 0; j < 4; ++j) K[a][j] = Pp[a][j] / S[j];
#pragma unroll
        for (int a = 0; a < 8; ++a) {
#pragma unroll
            for (int b = 0; b < 8; ++b) {
                float s = 0.f;
#pragma unroll
                for (int r = 0; r < 4; ++r) s = fmaf(K[a][r], Pp[r][b], s);
                C[a][b] = Pp[a][b] - s;
            }
        }
    }
#pragma unroll
    for (int a = 0; a < 8; ++a)
#pragma unroll
        for (int b = 0; b < 8; ++b) cov[(size_t)i * 64 + a * 8 + b] = C[a][b];
}

// ===========================================================================
// =================  FALLBACK PATH (R1 fp32 kernels)  =======================
// ===========================================================================
template<int BR>
__global__ __launch_bounds__(256)
void ffn_kernel(const float* __restrict__ X,
                const float* __restrict__ W1, const float* __restrict__ B1,
                const float* __restrict__ W2, const float* __restrict__ B2,
                float* __restrict__ Y)
{
    __shared__ float xs[BR][D];
    __shared__ float hs[BR][256];
    const int t = threadIdx.x;
    const int row0 = blockIdx.x * BR;

    for (int i = t; i < BR * D; i += 256) {
        int r = i >> 8, c = i & 255;
        xs[r][c] = X[(size_t)(row0 + r) * D + c];
    }
    __syncthreads();

    float a2[BR];
#pragma unroll
    for (int r = 0; r < BR; ++r) a2[r] = 0.f;

    for (int c = 0; c < DFF / 256; ++c) {
        const int hc = c * 256 + t;
        float a1[BR];
#pragma unroll
        for (int r = 0; r < BR; ++r) a1[r] = 0.f;

        const float* w1p = W1 + hc;
        for (int k = 0; k < D; k += 4) {
            float w0 = w1p[(size_t)(k + 0) * DFF];
            float w1v = w1p[(size_t)(k + 1) * DFF];
            float w2v = w1p[(size_t)(k + 2) * DFF];
            float w3 = w1p[(size_t)(k + 3) * DFF];
#pragma unroll
            for (int r = 0; r < BR; ++r) {
                float4 xv = *reinterpret_cast<const float4*>(&xs[r][k]);
                a1[r] = fmaf(xv.x, w0, a1[r]);
                a1[r] = fmaf(xv.y, w1v, a1[r]);
                a1[r] = fmaf(xv.z, w2v, a1[r]);
                a1[r] = fmaf(xv.w, w3, a1[r]);
            }
        }
        float b1v = B1[hc];
#pragma unroll
        for (int r = 0; r < BR; ++r) hs[r][t] = gelu_f(a1[r] + b1v);
        __syncthreads();

        const float* w2p = W2 + (size_t)c * 256 * D + t;
        for (int k = 0; k < 256; k += 4) {
            float w0 = w2p[(size_t)(k + 0) * D];
            float w1v = w2p[(size_t)(k + 1) * D];
            float w2v = w2p[(size_t)(k + 2) * D];
            float w3 = w2p[(size_t)(k + 3) * D];
#pragma unroll
            for (int r = 0; r < BR; ++r) {
                float4 hv = *reinterpret_cast<const float4*>(&hs[r][k]);
                a2[r] = fmaf(hv.x, w0, a2[r]);
                a2[r] = fmaf(hv.y, w1v, a2[r]);
                a2[r] = fmaf(hv.z, w2v, a2[r]);
                a2[r] = fmaf(hv.w, w3, a2[r]);
            }
        }
        __syncthreads();
    }

    float b2v = B2[t];
#pragma unroll
    for (int r = 0; r < BR; ++r) {
        Y[(size_t)(row0 + r) * D + t] = xs[r][t] + a2[r] + b2v;
    }
}

template<int BR>
__global__ __launch_bounds__(128)
void motion_kernel(const float* __restrict__ x1, const float* __restrict__ boxes,
                   const int* __restrict__ masks,
                   const float* __restrict__ MW1, const float* __restrict__ MB1,
                   const float* __restrict__ MW2, const float* __restrict__ MB2,
                   const float* __restrict__ MW3, const float* __restrict__ MB3,
                   float* __restrict__ Mout)
{
    __shared__ float ins[BR][264];
    __shared__ float h1[BR][MDIM];
    __shared__ float h2[BR][MDIM];
    const int t = threadIdx.x;
    const int row0 = blockIdx.x * BR;

    for (int i = t; i < BR * 264; i += 128) {
        int r = i / 264, c = i % 264;
        int row = row0 + r;
        float v;
        if (c < 256) {
            v = x1[(size_t)row * D + c];
        } else if (c < 260) {
            v = boxes[(size_t)row * 4 + (c - 256)];
        } else {
            int tt = (row / NB) % TT;
            int prev = (tt == 0) ? row : row - NB;
            int j = c - 260;
            v = boxes[(size_t)row * 4 + j] - boxes[(size_t)prev * 4 + j];
        }
        ins[r][c] = v;
    }
    __syncthreads();

    float a[BR];
#pragma unroll
    for (int r = 0; r < BR; ++r) a[r] = 0.f;
    for (int k = 0; k < 264; k += 4) {
        float w0 = MW1[(size_t)(k + 0) * MDIM + t];
        float w1 = MW1[(size_t)(k + 1) * MDIM + t];
        float w2 = MW1[(size_t)(k + 2) * MDIM + t];
        float w3 = MW1[(size_t)(k + 3) * MDIM + t];
#pragma unroll
        for (int r = 0; r < BR; ++r) {
            float4 xv = *reinterpret_cast<const float4*>(&ins[r][k]);
            a[r] = fmaf(xv.x, w0, a[r]);
            a[r] = fmaf(xv.y, w1, a[r]);
            a[r] = fmaf(xv.z, w2, a[r]);
            a[r] = fmaf(xv.w, w3, a[r]);
        }
    }
    float bb1 = MB1[t];
#pragma unroll
    for (int r = 0; r < BR; ++r) h1[r][t] = gelu_f(a[r] + bb1);
    __syncthreads();

#pragma unroll
    for (int r = 0; r < BR; ++r) a[r] = 0.f;
    for (int k = 0; k < MDIM; k += 4) {
        float w0 = MW2[(size_t)(k + 0) * MDIM + t];
        float w1 = MW2[(size_t)(k + 1) * MDIM + t];
        float w2 = MW2[(size_t)(k + 2) * MDIM + t];
        float w3 = MW2[(size_t)(k + 3) * MDIM + t];
#pragma unroll
        for (int r = 0; r < BR; ++r) {
            float4 xv = *reinterpret_cast<const float4*>(&h1[r][k]);
            a[r] = fmaf(xv.x, w0, a[r]);
            a[r] = fmaf(xv.y, w1, a[r]);
            a[r] = fmaf(xv.z, w2, a[r]);
            a[r] = fmaf(xv.w, w3, a[r]);
        }
    }
    float bb2 = MB2[t];
#pragma unroll
    for (int r = 0; r < BR; ++r) h2[r][t] = gelu_f(a[r] + bb2);
    __syncthreads();

#pragma unroll
    for (int r = 0; r < BR; ++r) a[r] = 0.f;
    for (int k = 0; k < MDIM; k += 4) {
        float w0 = MW3[(size_t)(k + 0) * MDIM + t];
        float w1 = MW3[(size_t)(k + 1) * MDIM + t];
        float w2 = MW3[(size_t)(k + 2) * MDIM + t];
        float w3 = MW3[(size_t)(k + 3) * MDIM + t];
#pragma unroll
        for (int r = 0; r < BR; ++r) {
            float4 xv = *reinterpret_cast<const float4*>(&h2[r][k]);
            a[r] = fmaf(xv.x, w0, a[r]);
            a[r] = fmaf(xv.y, w1, a[r]);
            a[r] = fmaf(xv.z, w2, a[r]);
            a[r] = fmaf(xv.w, w3, a[r]);
        }
    }
    float bb3 = MB3[t];
#pragma unroll
    for (int r = 0; r < BR; ++r) {
        float mf = (masks[row0 + r] != 0) ? 1.0f : 0.0f;
        Mout[(size_t)(row0 + r) * MDIM + t] = (a[r] + bb3) * mf;
    }
}

template<int BR>
__global__ __launch_bounds__(256)
void fusion_kernel(const float* __restrict__ x1, const float* __restrict__ m,
                   const float* __restrict__ FW1, const float* __restrict__ FB1,
                   const float* __restrict__ FW2, const float* __restrict__ FB2,
                   float* __restrict__ Y)
{
    __shared__ float fin[BR][384];
    __shared__ float h[BR][256];
    const int t = threadIdx.x;
    const int row0 = blockIdx.x * BR;

    for (int i = t; i < BR * 384; i += 256) {
        int r = i / 384, c = i % 384;
        int row = row0 + r;
        fin[r][c] = (c < 256) ? x1[(size_t)row * D + c]
                              : m[(size_t)row * MDIM + (c - 256)];
    }
    __syncthreads();

    float a[BR];
#pragma unroll
    for (int r = 0; r < BR; ++r) a[r] = 0.f;
    for (int k = 0; k < 384; k += 4) {
        float w0 = FW1[(size_t)(k + 0) * D + t];
        float w1 = FW1[(size_t)(k + 1) * D + t];
        float w2 = FW1[(size_t)(k + 2) * D + t];
        float w3 = FW1[(size_t)(k + 3) * D + t];
#pragma unroll
        for (int r = 0; r < BR; ++r) {
            float4 xv = *reinterpret_cast<const float4*>(&fin[r][k]);
            a[r] = fmaf(xv.x, w0, a[r]);
            a[r] = fmaf(xv.y, w1, a[r]);
            a[r] = fmaf(xv.z, w2, a[r]);
            a[r] = fmaf(xv.w, w3, a[r]);
        }
    }
    float fb = FB1[t];
#pragma unroll
    for (int r = 0; r < BR; ++r) h[r][t] = fmaxf(a[r] + fb, 0.f);
    __syncthreads();

    float a2[BR];
#pragma unroll
    for (int r = 0; r < BR; ++r) a2[r] = 0.f;
    for (int k = 0; k < D; k += 4) {
        float w0 = FW2[(size_t)(k + 0) * D + t];
        float w1 = FW2[(size_t)(k + 1) * D + t];
        float w2 = FW2[(size_t)(k + 2) * D + t];
        float w3 = FW2[(size_t)(k + 3) * D + t];
#pragma unroll
        for (int r = 0; r < BR; ++r) {
            float4 hv = *reinterpret_cast<const float4*>(&h[r][k]);
            a2[r] = fmaf(hv.x, w0, a2[r]);
            a2[r] = fmaf(hv.y, w1, a2[r]);
            a2[r] = fmaf(hv.z, w2, a2[r]);
            a2[r] = fmaf(hv.w, w3, a2[r]);
        }
    }
    float fb2v = FB2[t];
#pragma unroll
    for (int r = 0; r < BR; ++r) {
        Y[(size_t)(row0 + r) * D + t] = a2[r] + fb2v;
    }
}

// ===========================================================================
extern "C" void kernel_launch(void* const* d_in, const int* in_sizes, int n_in,
                              void* d_out, int out_size, void* d_ws, size_t ws_size,
                              hipStream_t stream)
{
    const float* feats = (const float*)d_in[0];
    const float* boxes = (const float*)d_in[1];
    const int*   masks = (const int*)d_in[2];
    const float* aw1 = (const float*)d_in[3];
    const float* ab1 = (const float*)d_in[4];
    const float* aw2 = (const float*)d_in[5];
    const float* ab2 = (const float*)d_in[6];
    const float* ng  = (const float*)d_in[7];
    const float* nb  = (const float*)d_in[8];
    const float* mw1 = (const float*)d_in[9];
    const float* mb1 = (const float*)d_in[10];
    const float* mw2 = (const float*)d_in[11];
    const float* mb2 = (const float*)d_in[12];
    const float* mw3 = (const float*)d_in[13];
    const float* mb3 = (const float*)d_in[14];
    const float* fw1 = (const float*)d_in[15];
    const float* fb1 = (const float*)d_in[16];
    const float* fw2 = (const float*)d_in[17];
    const float* fb2 = (const float*)d_in[18];
    const float* w1  = (const float*)d_in[19];
    const float* b1  = (const float*)d_in[20];
    const float* w2  = (const float*)d_in[21];
    const float* b2  = (const float*)d_in[22];
    const float* fng = (const float*)d_in[23];
    const float* fnb = (const float*)d_in[24];

    float* outx   = (float*)d_out;                   // R*256 — X lives here
    float* outst  = outx + (size_t)R_TOTAL * D;
    float* outcov = outst + (size_t)NTRACK * 8;

    // ---- ws layout (fast path) ----
    const size_t SZ_AW1 = 256 * 1024 * 4;
    const size_t SZ_AW2 = 1024 * 256 * 4;
    const size_t SZ_FW1 = 384 * 256 * 4;
    const size_t SZ_FW2 = 256 * 256 * 4;
    const size_t SZ_MW1 = 288 * 128 * 4;
    const size_t SZ_MW2 = 128 * 128 * 4;

    char* p = (char*)d_ws;
    ushort* aw1t = (ushort*)p;  p += SZ_AW1;
    ushort* aw2t = (ushort*)p;  p += SZ_AW2;
    ushort* w1t  = (ushort*)p;  p += SZ_AW1;
    ushort* w2t  = (ushort*)p;  p += SZ_AW2;
    ushort* fw1t = (ushort*)p;  p += SZ_FW1;
    ushort* fw2t = (ushort*)p;  p += SZ_FW2;
    ushort* mw1t = (ushort*)p;  p += SZ_MW1;
    ushort* mw2t = (ushort*)p;  p += SZ_MW2;
    ushort* mw3t = (ushort*)p;  p += SZ_MW2;
    float*  box8 = (float*)p;   p += (size_t)R_TOTAL * 8 * 4;     // 2.048 MB
    float*  M1   = (float*)p;   p += (size_t)R_TOTAL * 128 * 4;   // 32.768 MB
    float*  Hc   = (float*)p;                                     // chunk region
    size_t used = (size_t)(p - (char*)d_ws);
    const size_t HBLK = 128 * 1024 * 4;   // H bytes per 128-row block (fp32)

    long long availH = (long long)ws_size - (long long)used;
    int cb_max = (availH > 0) ? (int)(availH / (long long)HBLK) : 0;
    if (cb_max > NBLK) cb_max = NBLK;

    if (cb_max >= 1) {
        // ---------------- fast path: bf16x3 MFMA, row-chunked ----------------
        WPrepAll P;
        const float* srcs[9] = {aw1, aw2, w1, w2, fw1, fw2, mw1, mw2, mw3};
        ushort* dsts[9] = {aw1t, aw2t, w1t, w2t, fw1t, fw2t, mw1t, mw2t, mw3t};
        int Ks[9]    = {256, 1024, 256, 1024, 384, 256, 264, 128, 128};
        int Kpads[9] = {256, 1024, 256, 1024, 384, 256, 288, 128, 128};
        int logNs[9] = {10, 8, 10, 8, 8, 8, 7, 7, 7};
        int base = 0;
        for (int i = 0; i < 9; ++i) {
            P.src[i] = srcs[i]; P.dst[i] = dsts[i];
            P.K[i] = Ks[i]; P.Kpad[i] = Kpads[i]; P.logN[i] = logNs[i];
            P.base[i] = base;
            base += Kpads[i] << logNs[i];
        }
        P.base[9] = base;
        prep_weights<<<(base + 255) / 256, 256, 0, stream>>>(P);
        prep_box8<<<(R_TOTAL * 8 + 255) / 256, 256, 0, stream>>>(boxes, box8);

        // ---- FFN_a: outx = feats + FFN(feats), row-chunked ----
        for (int c0 = 0; c0 < NBLK; c0 += cb_max) {
            int cb = (NBLK - c0 < cb_max) ? (NBLK - c0) : cb_max;
            gemm_split<EP_GELU><<<dim3(cb, 8), 256, 0, stream>>>(
                feats, 256, nullptr, 0, aw1t, ab1, nullptr, nullptr, Hc, 1024, 8, c0, 0);
            gemm_split<EP_BIASRES><<<dim3(cb, 2), 256, 0, stream>>>(
                Hc, 1024, nullptr, 0, aw2t, ab2, feats, nullptr, outx, 256, 32, 0, c0);
        }
        // ---- LN1 in-place ----
        ln_kernel<<<R_TOTAL / 4, 256, 0, stream>>>(outx, ng, nb, outx);

        // ---- motion MLP (h1,h2 in Hc region), row-chunked ----
        {
            int cbm = cb_max * 4; if (cbm > NBLK) cbm = NBLK;   // 2×64KB per block
            float* h1 = Hc;
            float* h2 = Hc + (size_t)cbm * 128 * 128;
            for (int c0 = 0; c0 < NBLK; c0 += cbm) {
                int cb = (NBLK - c0 < cbm) ? (NBLK - c0) : cbm;
                gemm_split<EP_GELU><<<dim3(cb, 1), 256, 0, stream>>>(
                    outx, 256, box8, 8, mw1t, mb1, nullptr, nullptr, h1, 128, 9, c0, 0);
                gemm_split<EP_GELU><<<dim3(cb, 1), 256, 0, stream>>>(
                    h1, 128, nullptr, 0, mw2t, mb2, nullptr, nullptr, h2, 128, 4, 0, 0);
                gemm_split<EP_MASK><<<dim3(cb, 1), 256, 0, stream>>>(
                    h2, 128, nullptr, 0, mw3t, mb3, nullptr, masks, M1, 128, 4, 0, c0);
            }
        }

        // ---- fusion: outx = relu(concat(x,m)@fw1+fb1)@fw2+fb2, row-chunked ----
        {
            int cbf = cb_max * 4; if (cbf > NBLK) cbf = NBLK;   // 128KB per block
            float* hf = Hc;
            for (int c0 = 0; c0 < NBLK; c0 += cbf) {
                int cb = (NBLK - c0 < cbf) ? (NBLK - c0) : cbf;
                gemm_split<EP_RELU><<<dim3(cb, 2), 256, 0, stream>>>(
                    outx, 256, M1, 128, fw1t, fb1, nullptr, nullptr, hf, 256, 12, c0, 0);
                gemm_split<EP_BIAS><<<dim3(cb, 2), 256, 0, stream>>>(
                    hf, 256, nullptr, 0, fw2t, fb2, nullptr, nullptr, outx, 256, 8, 0, c0);
            }
        }

        // ---- FFN2: outx = x + FFN(x), row-chunked ----
        for (int c0 = 0; c0 < NBLK; c0 += cb_max) {
            int cb = (NBLK - c0 < cb_max) ? (NBLK - c0) : cb_max;
            gemm_split<EP_GELU><<<dim3(cb, 8), 256, 0, stream>>>(
                outx, 256, nullptr, 0, w1t, b1, nullptr, nullptr, Hc, 1024, 8, c0, 0);
            gemm_split<EP_BIASRES><<<dim3(cb, 2), 256, 0, stream>>>(
                Hc, 1024, nullptr, 0, w2t, b2, outx, nullptr, outx, 256, 32, 0, c0);
        }
        // ---- LN2 in-place ----
        ln_kernel<<<R_TOTAL / 4, 256, 0, stream>>>(outx, fng, fnb, outx);
    } else {
        // ---------------- fallback: R1 fp32 path ----------------
        float* m = (float*)d_ws;
        ffn_kernel<16><<<R_TOTAL / 16, 256, 0, stream>>>(feats, aw1, ab1, aw2, ab2, outx);
        ln_kernel<<<R_TOTAL / 4, 256, 0, stream>>>(outx, ng, nb, outx);
        motion_kernel<16><<<R_TOTAL / 16, 128, 0, stream>>>(outx, boxes, masks,
                                                            mw1, mb1, mw2, mb2, mw3, mb3, m);
        fusion_kernel<16><<<R_TOTAL / 16, 256, 0, stream>>>(outx, m, fw1, fb1, fw2, fb2, outx);
        ffn_kernel<16><<<R_TOTAL / 16, 256, 0, stream>>>(outx, w1, b1, w2, b2, outx);
        ln_kernel<<<R_TOTAL / 4, 256, 0, stream>>>(outx, fng, fnb, outx);
    }
    kalman_kernel<<<(NTRACK + 255) / 256, 256, 0, stream>>>(boxes, masks, outst, outcov);
}

// Round 6
// 1490.864 us; speedup vs baseline: 1.0021x; 1.0021x over previous
//
#include <hip/hip_runtime.h>
#include <hip/hip_bf16.h>
#include <math.h>

#define R_TOTAL 64000   // B*G*T*N
#define D 256
#define DFF 1024
#define MDIM 128
#define NB 500
#define TT 16
#define NTRACK 4000
#define NBLK 500        // R_TOTAL / 128

typedef __attribute__((ext_vector_type(8))) short bf8_t;   // 8 bf16
typedef __attribute__((ext_vector_type(4))) float f4_t;    // MFMA acc
typedef __attribute__((ext_vector_type(4))) ushort us4_t;

struct bfpair { ushort h, l; };

__device__ __forceinline__ float gelu_fast(float x) {
    float z = 1.5957691216057308f * (x + 0.044715f * x * x * x);
    return x / (1.0f + __expf(-z));
}
__device__ __forceinline__ float gelu_f(float x) {
    float x3 = x * x * x;
    float t = tanhf(0.7978845608028654f * (x + 0.044715f * x3));
    return 0.5f * x * (1.0f + t);
}
__device__ __forceinline__ float bf2f(ushort u) {
    return __uint_as_float(((uint)u) << 16);
}
__device__ __forceinline__ bfpair f2split(float v) {
    bfpair r;
    __hip_bfloat16 hb = __float2bfloat16(v);
    float hf = __bfloat162float(hb);
    __hip_bfloat16 lb = __float2bfloat16(v - hf);
    r.h = __hip_bfloat16_raw(hb).x;
    r.l = __hip_bfloat16_raw(lb).x;
    return r;
}

// ===========================================================================
// bf16x3-split GEMM, pre-split A planes (hi/lo bf16), tiled weights.
// Weight tiles: [colblk][kstep][plane2][n128][k32] bf16.
// LDS A-tile: [buf][plane][128][32] bf16 with chunk-XOR swizzle:
//   element (r,k) stored at chunk ((k>>3) ^ ((r>>1)&3)) -> 2-way banks (free).
// ===========================================================================

enum { EP_GELU = 0, EP_RELU = 1, EP_BIAS = 2, EP_BIASRES = 3, EP_MASK = 4 };
enum { RES_NONE = 0, RES_F32 = 1, RES_SPLIT = 2 };
enum { OUT_F32 = 0, OUT_SPLIT = 1 };

template<int MODE, int RES, int OUT>
__global__ __launch_bounds__(256, 3)
void gemm_bf16(const ushort* __restrict__ A1h, const ushort* __restrict__ A1l, int K1,
               const ushort* __restrict__ A2h, const ushort* __restrict__ A2l, int K2w,
               const ushort* __restrict__ Wt,
               const float* __restrict__ bias,
               const float* __restrict__ resF,
               const ushort* __restrict__ resH, const ushort* __restrict__ resL,
               const int* __restrict__ mask,
               float* __restrict__ outF, ushort* __restrict__ outH, ushort* __restrict__ outL,
               int N, int nk, int aBase, int oBase)
{
    __shared__ __align__(16) ushort sA[2][2][128][32];   // 32 KB

    const int tid = threadIdx.x;
    const int lane = tid & 63, wid = tid >> 6;
    const int wr = wid >> 1, wc = wid & 1;
    const int colblk = blockIdx.y;
    const int row0A = (aBase + blockIdx.x) * 128;
    const int row0O = (oBase + blockIdx.x) * 128;
    const int lm = lane & 15, lg = lane >> 4;

    f4_t acc[4][4];
#pragma unroll
    for (int i = 0; i < 4; ++i)
#pragma unroll
        for (int j = 0; j < 4; ++j) acc[i][j] = (f4_t)0.f;

    auto stage = [&](int ks, int buf) {
        const int k0 = ks * 32;
        const ushort *sh, *sl; int stride, kc;
        if (k0 < K1) { sh = A1h; sl = A1l; stride = K1; kc = k0; }
        else         { sh = A2h; sl = A2l; stride = K2w; kc = k0 - K1; }
        const int r0 = tid >> 2;          // 0..63
        const int c  = tid & 3;           // k-chunk 0..3
        const size_t off0 = (size_t)(row0A + r0) * stride + kc + c * 8;
        const size_t off1 = off0 + (size_t)64 * stride;
        bf8_t h0 = *(const bf8_t*)(sh + off0);
        bf8_t h1 = *(const bf8_t*)(sh + off1);
        bf8_t l0 = *(const bf8_t*)(sl + off0);
        bf8_t l1 = *(const bf8_t*)(sl + off1);
        const int cs = (c ^ ((r0 >> 1) & 3)) * 8;   // (r0+64) has same swizzle
        *(bf8_t*)&sA[buf][0][r0][cs]      = h0;
        *(bf8_t*)&sA[buf][0][r0 + 64][cs] = h1;
        *(bf8_t*)&sA[buf][1][r0][cs]      = l0;
        *(bf8_t*)&sA[buf][1][r0 + 64][cs] = l1;
    };

    auto compute = [&](int buf, int ks) {
        const ushort* wb = Wt + (((size_t)(colblk * nk + ks)) * 2) * 4096
                              + (wc * 64 + lm) * 32 + lg * 8;
        bf8_t Bh[4], Bl[4];
#pragma unroll
        for (int ct = 0; ct < 4; ++ct) {
            Bh[ct] = *(const bf8_t*)(wb + ct * 512);          // hi plane
            Bl[ct] = *(const bf8_t*)(wb + 4096 + ct * 512);   // lo plane
        }
#pragma unroll
        for (int rt = 0; rt < 4; ++rt) {
            int r = wr * 64 + rt * 16 + lm;
            int cs = (lg ^ ((r >> 1) & 3)) * 8;
            bf8_t Ah = *(const bf8_t*)&sA[buf][0][r][cs];
            bf8_t Al = *(const bf8_t*)&sA[buf][1][r][cs];
#pragma unroll
            for (int ct = 0; ct < 4; ++ct) {
                acc[rt][ct] = __builtin_amdgcn_mfma_f32_16x16x32_bf16(Ah, Bh[ct], acc[rt][ct], 0, 0, 0);
                acc[rt][ct] = __builtin_amdgcn_mfma_f32_16x16x32_bf16(Ah, Bl[ct], acc[rt][ct], 0, 0, 0);
                acc[rt][ct] = __builtin_amdgcn_mfma_f32_16x16x32_bf16(Al, Bh[ct], acc[rt][ct], 0, 0, 0);
            }
        }
    };

    stage(0, 0);
    __syncthreads();
    for (int ks = 0; ks < nk; ++ks) {
        int cur = ks & 1;
        if (ks + 1 < nk) stage(ks + 1, cur ^ 1);
        compute(cur, ks);
        __syncthreads();
    }

    // Epilogue: C/D layout col=lane&15, row=(lane>>4)*4+reg
#pragma unroll
    for (int ct = 0; ct < 4; ++ct) {
        int col = colblk * 128 + wc * 64 + ct * 16 + lm;
        float bv = bias[col];
#pragma unroll
        for (int rt = 0; rt < 4; ++rt) {
#pragma unroll
            for (int rg = 0; rg < 4; ++rg) {
                int row = row0O + wr * 64 + rt * 16 + lg * 4 + rg;
                size_t idx = (size_t)row * N + col;
                float v = acc[rt][ct][rg] + bv;
                if (MODE == EP_GELU)      v = gelu_fast(v);
                else if (MODE == EP_RELU) v = fmaxf(v, 0.f);
                else if (MODE == EP_MASK) v *= (mask[row] != 0) ? 1.0f : 0.0f;
                if (MODE == EP_BIASRES) {
                    if (RES == RES_F32)   v += resF[idx];
                    if (RES == RES_SPLIT) v += bf2f(resH[idx]) + bf2f(resL[idx]);
                }
                if (OUT == OUT_F32) {
                    outF[idx] = v;
                } else {
                    bfpair s = f2split(v);
                    outH[idx] = s.h; outL[idx] = s.l;
                }
            }
        }
    }
}

// --------------------- weight split+tile prep ------------------------------
struct WPrepAll {
    const float* src[9];
    ushort* dst[9];
    int K[9], Kpad[9], logN[9];
    int base[10];
};

__global__ __launch_bounds__(256)
void prep_weights(WPrepAll P)
{
    int idx = blockIdx.x * 256 + threadIdx.x;
    int total = P.base[9];
    for (; idx < total; idx += gridDim.x * 256) {
        int d = 0;
        while (idx >= P.base[d + 1]) ++d;
        int local = idx - P.base[d];
        int N = 1 << P.logN[d];
        int n = local & (N - 1);
        int k = local >> P.logN[d];
        float w = (k < P.K[d]) ? P.src[d][(size_t)k * N + n] : 0.0f;
        bfpair s = f2split(w);
        int colblk = n >> 7, nloc = n & 127;
        int kstep = k >> 5, kk = k & 31;
        int nks = P.Kpad[d] >> 5;
        size_t off = (((size_t)(colblk * nks + kstep)) * 2) * 4096 + (size_t)nloc * 32 + kk;
        P.dst[d][off] = s.h;
        P.dst[d][off + 4096] = s.l;
    }
}

// --------------------- split fp32 -> hi/lo planes --------------------------
__global__ __launch_bounds__(256)
void split_f32(const float* __restrict__ src, ushort* __restrict__ dh,
               ushort* __restrict__ dl, int n4)
{
    int i = blockIdx.x * 256 + threadIdx.x;
    if (i >= n4) return;
    float4 v = ((const float4*)src)[i];
    us4_t h, l;
    bfpair s0 = f2split(v.x), s1 = f2split(v.y), s2 = f2split(v.z), s3 = f2split(v.w);
    h.x = s0.h; l.x = s0.l;
    h.y = s1.h; l.y = s1.l;
    h.z = s2.h; l.z = s2.l;
    h.w = s3.h; l.w = s3.l;
    ((us4_t*)dh)[i] = h;
    ((us4_t*)dl)[i] = l;
}

// --------------------- box32 = [boxes(4)|vel(4)|0...] hi/lo ----------------
__global__ __launch_bounds__(256)
void prep_box32s(const float* __restrict__ boxes, ushort* __restrict__ bh,
                 ushort* __restrict__ bl)
{
    int idx = blockIdx.x * 256 + threadIdx.x;
    if (idx >= R_TOTAL * 32) return;
    int row = idx >> 5, c = idx & 31;
    float v = 0.0f;
    if (c < 4) {
        v = boxes[(size_t)row * 4 + c];
    } else if (c < 8) {
        int tt = (row / NB) % TT;
        int prev = (tt == 0) ? row : row - NB;
        int j = c - 4;
        v = boxes[(size_t)row * 4 + j] - boxes[(size_t)prev * 4 + j];
    }
    bfpair s = f2split(v);
    bh[idx] = s.h; bl[idx] = s.l;
}

// --------------------- LayerNorm on split planes ---------------------------
template<int OUTF>   // 0: split out, 1: f32 out
__global__ __launch_bounds__(256)
void ln_split(const ushort* __restrict__ xh, const ushort* __restrict__ xl,
              const float* __restrict__ g, const float* __restrict__ b,
              ushort* __restrict__ oh, ushort* __restrict__ ol,
              float* __restrict__ of)
{
    const int lane = threadIdx.x & 63;
    const int wave = threadIdx.x >> 6;
    const size_t row = (size_t)blockIdx.x * 4 + wave;
    us4_t hv = ((const us4_t*)(xh + row * D))[lane];
    us4_t lv = ((const us4_t*)(xl + row * D))[lane];
    float x[4];
#pragma unroll
    for (int j = 0; j < 4; ++j) x[j] = bf2f(hv[j]) + bf2f(lv[j]);
    float s = x[0] + x[1] + x[2] + x[3];
#pragma unroll
    for (int m = 32; m >= 1; m >>= 1) s += __shfl_xor(s, m, 64);
    float mu = s * (1.0f / 256.0f);
    float d0 = x[0] - mu, d1 = x[1] - mu, d2 = x[2] - mu, d3 = x[3] - mu;
    float q = d0 * d0 + d1 * d1 + d2 * d2 + d3 * d3;
#pragma unroll
    for (int m = 32; m >= 1; m >>= 1) q += __shfl_xor(q, m, 64);
    float var = q * (1.0f / 256.0f);
    float sc = 1.0f / sqrtf(var + 1e-5f);
    float4 gv = reinterpret_cast<const float4*>(g)[lane];
    float4 bv = reinterpret_cast<const float4*>(b)[lane];
    float o0 = d0 * sc * gv.x + bv.x;
    float o1 = d1 * sc * gv.y + bv.y;
    float o2 = d2 * sc * gv.z + bv.z;
    float o3 = d3 * sc * gv.w + bv.w;
    if (OUTF) {
        float4 o = {o0, o1, o2, o3};
        reinterpret_cast<float4*>(of + row * D)[lane] = o;
    } else {
        us4_t h, l;
        bfpair s0 = f2split(o0), s1 = f2split(o1), s2 = f2split(o2), s3 = f2split(o3);
        h.x = s0.h; l.x = s0.l;
        h.y = s1.h; l.y = s1.l;
        h.z = s2.h; l.z = s2.l;
        h.w = s3.h; l.w = s3.l;
        ((us4_t*)(oh + row * D))[lane] = h;
        ((us4_t*)(ol + row * D))[lane] = l;
    }
}

// ---------------------------------------------------------------------------
__global__ __launch_bounds__(256)
void kalman_kernel(const float* __restrict__ boxes, const int* __restrict__ masks,
                   float* __restrict__ st, float* __restrict__ cov)
{
    int i = blockIdx.x * blockDim.x + threadIdx.x;
    if (i >= NTRACK) return;
    int n = i % NB;
    int bg = i / NB;
    size_t rowlast = ((size_t)bg * TT + (TT - 1)) * NB + n;

    float z[4];
#pragma unroll
    for (int j = 0; j < 4; ++j) z[j] = boxes[rowlast * 4 + j];
    int mask = masks[rowlast];

#pragma unroll
    for (int j = 0; j < 4; ++j) st[(size_t)i * 8 + j] = z[j];
#pragma unroll
    for (int j = 4; j < 8; ++j) st[(size_t)i * 8 + j] = 0.0f;

    float C[8][8];
    if (mask != 0) {
#pragma unroll
        for (int a = 0; a < 8; ++a)
#pragma unroll
            for (int b = 0; b < 8; ++b) C[a][b] = (a == b) ? 1.0f : 0.0f;
    } else {
        float Pp[8][8];
#pragma unroll
        for (int a = 0; a < 8; ++a) {
#pragma unroll
            for (int b = 0; b < 8; ++b) {
                float s = 0.f;
#pragma unroll
                for (int k = 0; k < 8; ++k) {
                    float Fa = (a == k ? 1.f : 0.f) + ((a < 4 && k == a + 4) ? 1.f : 0.f);
                    float Fb = (b == k ? 1.f : 0.f) + ((b < 4 && k == b + 4) ? 1.f : 0.f);
                    s = fmaf(Fa, Fb, s);
                }
                Pp[a][b] = s + ((a == b) ? 0.01f : 0.0f);
            }
        }
        float S[4];
#pragma unroll
        for (int j = 0; j < 4; ++j) S[j] = Pp[j][j] + 0.1f;
        float K[8][4];
#pragma unroll
        for (int a = 0; a < 8; ++a)
#pragma unroll
            for (int j = 0; j < 4; ++j) K[a][j] = Pp[a][j] / S[j];
#pragma unroll
        for (int a = 0; a < 8; ++a) {
#pragma unroll
            for (int b = 0; b < 8; ++b) {
                float s = 0.f;
#pragma unroll
                for (int r = 0; r < 4; ++r) s = fmaf(K[a][r], Pp[r][b], s);
                C[a][b] = Pp[a][b] - s;
            }
        }
    }
#pragma unroll
    for (int a = 0; a < 8; ++a)
#pragma unroll
        for (int b = 0; b < 8; ++b) cov[(size_t)i * 64 + a * 8 + b] = C[a][b];
}

// ===========================================================================
// =================  FALLBACK PATH (R1 fp32 kernels)  =======================
// ===========================================================================
__global__ __launch_bounds__(256)
void ln_kernel(const float* __restrict__ X, const float* __restrict__ g,
               const float* __restrict__ b, float* __restrict__ Y)
{
    const int lane = threadIdx.x & 63;
    const int wave = threadIdx.x >> 6;
    const size_t row = (size_t)blockIdx.x * 4 + wave;
    float4 v = reinterpret_cast<const float4*>(X + row * D)[lane];
    float s = v.x + v.y + v.z + v.w;
#pragma unroll
    for (int m = 32; m >= 1; m >>= 1) s += __shfl_xor(s, m, 64);
    float mu = s * (1.0f / 256.0f);
    float4 d = {v.x - mu, v.y - mu, v.z - mu, v.w - mu};
    float q = d.x * d.x + d.y * d.y + d.z * d.z + d.w * d.w;
#pragma unroll
    for (int m = 32; m >= 1; m >>= 1) q += __shfl_xor(q, m, 64);
    float var = q * (1.0f / 256.0f);
    float sc = 1.0f / sqrtf(var + 1e-5f);
    float4 gv = reinterpret_cast<const float4*>(g)[lane];
    float4 bv = reinterpret_cast<const float4*>(b)[lane];
    float4 o = {d.x * sc * gv.x + bv.x, d.y * sc * gv.y + bv.y,
                d.z * sc * gv.z + bv.z, d.w * sc * gv.w + bv.w};
    reinterpret_cast<float4*>(Y + row * D)[lane] = o;
}

template<int BR>
__global__ __launch_bounds__(256)
void ffn_kernel(const float* __restrict__ X,
                const float* __restrict__ W1, const float* __restrict__ B1,
                const float* __restrict__ W2, const float* __restrict__ B2,
                float* __restrict__ Y)
{
    __shared__ float xs[BR][D];
    __shared__ float hs[BR][256];
    const int t = threadIdx.x;
    const int row0 = blockIdx.x * BR;

    for (int i = t; i < BR * D; i += 256) {
        int r = i >> 8, c = i & 255;
        xs[r][c] = X[(size_t)(row0 + r) * D + c];
    }
    __syncthreads();

    float a2[BR];
#pragma unroll
    for (int r = 0; r < BR; ++r) a2[r] = 0.f;

    for (int c = 0; c < DFF / 256; ++c) {
        const int hc = c * 256 + t;
        float a1[BR];
#pragma unroll
        for (int r = 0; r < BR; ++r) a1[r] = 0.f;

        const float* w1p = W1 + hc;
        for (int k = 0; k < D; k += 4) {
            float w0 = w1p[(size_t)(k + 0) * DFF];
            float w1v = w1p[(size_t)(k + 1) * DFF];
            float w2v = w1p[(size_t)(k + 2) * DFF];
            float w3 = w1p[(size_t)(k + 3) * DFF];
#pragma unroll
            for (int r = 0; r < BR; ++r) {
                float4 xv = *reinterpret_cast<const float4*>(&xs[r][k]);
                a1[r] = fmaf(xv.x, w0, a1[r]);
                a1[r] = fmaf(xv.y, w1v, a1[r]);
                a1[r] = fmaf(xv.z, w2v, a1[r]);
                a1[r] = fmaf(xv.w, w3, a1[r]);
            }
        }
        float b1v = B1[hc];
#pragma unroll
        for (int r = 0; r < BR; ++r) hs[r][t] = gelu_f(a1[r] + b1v);
        __syncthreads();

        const float* w2p = W2 + (size_t)c * 256 * D + t;
        for (int k = 0; k < 256; k += 4) {
            float w0 = w2p[(size_t)(k + 0) * D];
            float w1v = w2p[(size_t)(k + 1) * D];
            float w2v = w2p[(size_t)(k + 2) * D];
            float w3 = w2p[(size_t)(k + 3) * D];
#pragma unroll
            for (int r = 0; r < BR; ++r) {
                float4 hv = *reinterpret_cast<const float4*>(&hs[r][k]);
                a2[r] = fmaf(hv.x, w0, a2[r]);
                a2[r] = fmaf(hv.y, w1v, a2[r]);
                a2[r] = fmaf(hv.z, w2v, a2[r]);
                a2[r] = fmaf(hv.w, w3, a2[r]);
            }
        }
        __syncthreads();
    }

    float b2v = B2[t];
#pragma unroll
    for (int r = 0; r < BR; ++r) {
        Y[(size_t)(row0 + r) * D + t] = xs[r][t] + a2[r] + b2v;
    }
}

template<int BR>
__global__ __launch_bounds__(128)
void motion_kernel(const float* __restrict__ x1, const float* __restrict__ boxes,
                   const int* __restrict__ masks,
                   const float* __restrict__ MW1, const float* __restrict__ MB1,
                   const float* __restrict__ MW2, const float* __restrict__ MB2,
                   const float* __restrict__ MW3, const float* __restrict__ MB3,
                   float* __restrict__ Mout)
{
    __shared__ float ins[BR][264];
    __shared__ float h1[BR][MDIM];
    __shared__ float h2[BR][MDIM];
    const int t = threadIdx.x;
    const int row0 = blockIdx.x * BR;

    for (int i = t; i < BR * 264; i += 128) {
        int r = i / 264, c = i % 264;
        int row = row0 + r;
        float v;
        if (c < 256) {
            v = x1[(size_t)row * D + c];
        } else if (c < 260) {
            v = boxes[(size_t)row * 4 + (c - 256)];
        } else {
            int tt = (row / NB) % TT;
            int prev = (tt == 0) ? row : row - NB;
            int j = c - 260;
            v = boxes[(size_t)row * 4 + j] - boxes[(size_t)prev * 4 + j];
        }
        ins[r][c] = v;
    }
    __syncthreads();

    float a[BR];
#pragma unroll
    for (int r = 0; r < BR; ++r) a[r] = 0.f;
    for (int k = 0; k < 264; k += 4) {
        float w0 = MW1[(size_t)(k + 0) * MDIM + t];
        float w1 = MW1[(size_t)(k + 1) * MDIM + t];
        float w2 = MW1[(size_t)(k + 2) * MDIM + t];
        float w3 = MW1[(size_t)(k + 3) * MDIM + t];
#pragma unroll
        for (int r = 0; r < BR; ++r) {
            float4 xv = *reinterpret_cast<const float4*>(&ins[r][k]);
            a[r] = fmaf(xv.x, w0, a[r]);
            a[r] = fmaf(xv.y, w1, a[r]);
            a[r] = fmaf(xv.z, w2, a[r]);
            a[r] = fmaf(xv.w, w3, a[r]);
        }
    }
    float bb1 = MB1[t];
#pragma unroll
    for (int r = 0; r < BR; ++r) h1[r][t] = gelu_f(a[r] + bb1);
    __syncthreads();

#pragma unroll
    for (int r = 0; r < BR; ++r) a[r] = 0.f;
    for (int k = 0; k < MDIM; k += 4) {
        float w0 = MW2[(size_t)(k + 0) * MDIM + t];
        float w1 = MW2[(size_t)(k + 1) * MDIM + t];
        float w2 = MW2[(size_t)(k + 2) * MDIM + t];
        float w3 = MW2[(size_t)(k + 3) * MDIM + t];
#pragma unroll
        for (int r = 0; r < BR; ++r) {
            float4 xv = *reinterpret_cast<const float4*>(&h1[r][k]);
            a[r] = fmaf(xv.x, w0, a[r]);
            a[r] = fmaf(xv.y, w1, a[r]);
            a[r] = fmaf(xv.z, w2, a[r]);
            a[r] = fmaf(xv.w, w3, a[r]);
        }
    }
    float bb2 = MB2[t];
#pragma unroll
    for (int r = 0; r < BR; ++r) h2[r][t] = gelu_f(a[r] + bb2);
    __syncthreads();

#pragma unroll
    for (int r = 0; r < BR; ++r) a[r] = 0.f;
    for (int k = 0; k < MDIM; k += 4) {
        float w0 = MW3[(size_t)(k + 0) * MDIM + t];
        float w1 = MW3[(size_t)(k + 1) * MDIM + t];
        float w2 = MW3[(size_t)(k + 2) * MDIM + t];
        float w3 = MW3[(size_t)(k + 3) * MDIM + t];
#pragma unroll
        for (int r = 0; r < BR; ++r) {
            float4 xv = *reinterpret_cast<const float4*>(&h2[r][k]);
            a[r] = fmaf(xv.x, w0, a[r]);
            a[r] = fmaf(xv.y, w1, a[r]);
            a[r] = fmaf(xv.z, w2, a[r]);
            a[r] = fmaf(xv.w, w3, a[r]);
        }
    }
    float bb3 = MB3[t];
#pragma unroll
    for (int r = 0; r < BR; ++r) {
        float mf = (masks[row0 + r] != 0) ? 1.0f : 0.0f;
        Mout[(size_t)(row0 + r) * MDIM + t] = (a[r] + bb3) * mf;
    }
}

template<int BR>
__global__ __launch_bounds__(256)
void fusion_kernel(const float* __restrict__ x1, const float* __restrict__ m,
                   const float* __restrict__ FW1, const float* __restrict__ FB1,
                   const float* __restrict__ FW2, const float* __restrict__ FB2,
                   float* __restrict__ Y)
{
    __shared__ float fin[BR][384];
    __shared__ float h[BR][256];
    const int t = threadIdx.x;
    const int row0 = blockIdx.x * BR;

    for (int i = t; i < BR * 384; i += 256) {
        int r = i / 384, c = i % 384;
        int row = row0 + r;
        fin[r][c] = (c < 256) ? x1[(size_t)row * D + c]
                              : m[(size_t)row * MDIM + (c - 256)];
    }
    __syncthreads();

    float a[BR];
#pragma unroll
    for (int r = 0; r < BR; ++r) a[r] = 0.f;
    for (int k = 0; k < 384; k += 4) {
        float w0 = FW1[(size_t)(k + 0) * D + t];
        float w1 = FW1[(size_t)(k + 1) * D + t];
        float w2 = FW1[(size_t)(k + 2) * D + t];
        float w3 = FW1[(size_t)(k + 3) * D + t];
#pragma unroll
        for (int r = 0; r < BR; ++r) {
            float4 xv = *reinterpret_cast<const float4*>(&fin[r][k]);
            a[r] = fmaf(xv.x, w0, a[r]);
            a[r] = fmaf(xv.y, w1, a[r]);
            a[r] = fmaf(xv.z, w2, a[r]);
            a[r] = fmaf(xv.w, w3, a[r]);
        }
    }
    float fb = FB1[t];
#pragma unroll
    for (int r = 0; r < BR; ++r) h[r][t] = fmaxf(a[r] + fb, 0.f);
    __syncthreads();

    float a2[BR];
#pragma unroll
    for (int r = 0; r < BR; ++r) a2[r] = 0.f;
    for (int k = 0; k < D; k += 4) {
        float w0 = FW2[(size_t)(k + 0) * D + t];
        float w1 = FW2[(size_t)(k + 1) * D + t];
        float w2 = FW2[(size_t)(k + 2) * D + t];
        float w3 = FW2[(size_t)(k + 3) * D + t];
#pragma unroll
        for (int r = 0; r < BR; ++r) {
            float4 hv = *reinterpret_cast<const float4*>(&h[r][k]);
            a2[r] = fmaf(hv.x, w0, a2[r]);
            a2[r] = fmaf(hv.y, w1, a2[r]);
            a2[r] = fmaf(hv.z, w2, a2[r]);
            a2[r] = fmaf(hv.w, w3, a2[r]);
        }
    }
    float fb2v = FB2[t];
#pragma unroll
    for (int r = 0; r < BR; ++r) {
        Y[(size_t)(row0 + r) * D + t] = a2[r] + fb2v;
    }
}

// ===========================================================================
extern "C" void kernel_launch(void* const* d_in, const int* in_sizes, int n_in,
                              void* d_out, int out_size, void* d_ws, size_t ws_size,
                              hipStream_t stream)
{
    const float* feats = (const float*)d_in[0];
    const float* boxes = (const float*)d_in[1];
    const int*   masks = (const int*)d_in[2];
    const float* aw1 = (const float*)d_in[3];
    const float* ab1 = (const float*)d_in[4];
    const float* aw2 = (const float*)d_in[5];
    const float* ab2 = (const float*)d_in[6];
    const float* ng  = (const float*)d_in[7];
    const float* nb  = (const float*)d_in[8];
    const float* mw1 = (const float*)d_in[9];
    const float* mb1 = (const float*)d_in[10];
    const float* mw2 = (const float*)d_in[11];
    const float* mb2 = (const float*)d_in[12];
    const float* mw3 = (const float*)d_in[13];
    const float* mb3 = (const float*)d_in[14];
    const float* fw1 = (const float*)d_in[15];
    const float* fb1 = (const float*)d_in[16];
    const float* fw2 = (const float*)d_in[17];
    const float* fb2 = (const float*)d_in[18];
    const float* w1  = (const float*)d_in[19];
    const float* b1  = (const float*)d_in[20];
    const float* w2  = (const float*)d_in[21];
    const float* b2  = (const float*)d_in[22];
    const float* fng = (const float*)d_in[23];
    const float* fnb = (const float*)d_in[24];

    float* outx   = (float*)d_out;
    float* outst  = outx + (size_t)R_TOTAL * D;
    float* outcov = outst + (size_t)NTRACK * 8;

    // ---- ws layout (fast path) ----
    const size_t PLANE_D  = (size_t)R_TOTAL * D * 2;      // 32,768,000 B (bf16 R x 256)
    const size_t PLANE_M  = (size_t)R_TOTAL * MDIM * 2;   // 16,384,000 B
    char* p = (char*)d_ws;
    ushort* aw1t = (ushort*)p;  p += 1048576;
    ushort* aw2t = (ushort*)p;  p += 1048576;
    ushort* w1t  = (ushort*)p;  p += 1048576;
    ushort* w2t  = (ushort*)p;  p += 1048576;
    ushort* fw1t = (ushort*)p;  p += 393216;
    ushort* fw2t = (ushort*)p;  p += 262144;
    ushort* mw1t = (ushort*)p;  p += 147456;
    ushort* mw2t = (ushort*)p;  p += 65536;
    ushort* mw3t = (ushort*)p;  p += 65536;
    ushort* b32h = (ushort*)p;  p += (size_t)R_TOTAL * 32 * 2;   // 4,096,000
    ushort* b32l = (ushort*)p;  p += (size_t)R_TOTAL * 32 * 2;
    ushort* fsh  = (ushort*)p;  p += PLANE_D;   // feats split; later m1 planes
    ushort* fsl  = (ushort*)p;  p += PLANE_D;
    ushort* x1h  = (ushort*)p;  p += PLANE_D;   // X1 / X2
    ushort* x1l  = (ushort*)p;  p += PLANE_D;
    ushort* Th   = (ushort*)p;  p += PLANE_D;   // T (pre-LN) / h1,h2 / hf
    ushort* Tl   = (ushort*)p;  p += PLANE_D;
    char*   Hc   = p;                           // chunk region (H hi/lo)
    size_t used = (size_t)(p - (char*)d_ws);

    const size_t HBLK = (size_t)128 * DFF * 4;  // 524,288 B per 128-row block (hi+lo)
    long long availH = (long long)ws_size - (long long)used;
    int cb_max = (availH > 0) ? (int)(availH / (long long)HBLK) : 0;
    if (cb_max > NBLK) cb_max = NBLK;

    // aliases
    ushort* m1h = fsh;                              // M1 hi (feats-split dead)
    ushort* m1l = fsh + PLANE_M / 2;                // ushort units
    ushort* h1h = Th;
    ushort* h1l = Th + PLANE_M / 2;
    ushort* h2h = Tl;
    ushort* h2l = Tl + PLANE_M / 2;
    ushort* hfh = Th;
    ushort* hfl = Tl;

    if (cb_max >= 1) {
        // ---------------- fast path ----------------
        WPrepAll P;
        const float* srcs[9] = {aw1, aw2, w1, w2, fw1, fw2, mw1, mw2, mw3};
        ushort* dsts[9] = {aw1t, aw2t, w1t, w2t, fw1t, fw2t, mw1t, mw2t, mw3t};
        int Ks[9]    = {256, 1024, 256, 1024, 384, 256, 264, 128, 128};
        int Kpads[9] = {256, 1024, 256, 1024, 384, 256, 288, 128, 128};
        int logNs[9] = {10, 8, 10, 8, 8, 8, 7, 7, 7};
        int base = 0;
        for (int i = 0; i < 9; ++i) {
            P.src[i] = srcs[i]; P.dst[i] = dsts[i];
            P.K[i] = Ks[i]; P.Kpad[i] = Kpads[i]; P.logN[i] = logNs[i];
            P.base[i] = base;
            base += Kpads[i] << logNs[i];
        }
        P.base[9] = base;
        prep_weights<<<(base + 255) / 256, 256, 0, stream>>>(P);
        prep_box32s<<<(R_TOTAL * 32 + 255) / 256, 256, 0, stream>>>(boxes, b32h, b32l);
        split_f32<<<(R_TOTAL * D / 4 + 255) / 256, 256, 0, stream>>>(
            feats, fsh, fsl, R_TOTAL * D / 4);

        ushort* Hh = (ushort*)Hc;   // size cb*128*1024 ushorts each
        // ---- FFN_a: T = feats + FFN(feats) ----
        for (int c0 = 0; c0 < NBLK; c0 += cb_max) {
            int cb = (NBLK - c0 < cb_max) ? (NBLK - c0) : cb_max;
            ushort* Hl = Hh + (size_t)cb * 128 * DFF;
            gemm_bf16<EP_GELU, RES_NONE, OUT_SPLIT><<<dim3(cb, 8), 256, 0, stream>>>(
                fsh, fsl, 256, nullptr, nullptr, 0, aw1t, ab1,
                nullptr, nullptr, nullptr, nullptr,
                nullptr, Hh, Hl, DFF, 8, c0, 0);
            gemm_bf16<EP_BIASRES, RES_F32, OUT_SPLIT><<<dim3(cb, 2), 256, 0, stream>>>(
                Hh, Hl, 1024, nullptr, nullptr, 0, aw2t, ab2,
                feats, nullptr, nullptr, nullptr,
                nullptr, Th, Tl, D, 32, 0, c0);
        }
        // ---- LN1: X1 = LN(T) ----
        ln_split<0><<<R_TOTAL / 4, 256, 0, stream>>>(Th, Tl, ng, nb, x1h, x1l, nullptr);

        // ---- motion MLP (full-row launches) ----
        gemm_bf16<EP_GELU, RES_NONE, OUT_SPLIT><<<dim3(NBLK, 1), 256, 0, stream>>>(
            x1h, x1l, 256, b32h, b32l, 32, mw1t, mb1,
            nullptr, nullptr, nullptr, nullptr,
            nullptr, h1h, h1l, MDIM, 9, 0, 0);
        gemm_bf16<EP_GELU, RES_NONE, OUT_SPLIT><<<dim3(NBLK, 1), 256, 0, stream>>>(
            h1h, h1l, 128, nullptr, nullptr, 0, mw2t, mb2,
            nullptr, nullptr, nullptr, nullptr,
            nullptr, h2h, h2l, MDIM, 4, 0, 0);
        gemm_bf16<EP_MASK, RES_NONE, OUT_SPLIT><<<dim3(NBLK, 1), 256, 0, stream>>>(
            h2h, h2l, 128, nullptr, nullptr, 0, mw3t, mb3,
            nullptr, nullptr, nullptr, masks,
            nullptr, m1h, m1l, MDIM, 4, 0, 0);

        // ---- fusion ----
        gemm_bf16<EP_RELU, RES_NONE, OUT_SPLIT><<<dim3(NBLK, 2), 256, 0, stream>>>(
            x1h, x1l, 256, m1h, m1l, 128, fw1t, fb1,
            nullptr, nullptr, nullptr, nullptr,
            nullptr, hfh, hfl, D, 12, 0, 0);
        gemm_bf16<EP_BIAS, RES_NONE, OUT_SPLIT><<<dim3(NBLK, 2), 256, 0, stream>>>(
            hfh, hfl, 256, nullptr, nullptr, 0, fw2t, fb2,
            nullptr, nullptr, nullptr, nullptr,
            nullptr, x1h, x1l, D, 8, 0, 0);       // X2 overwrites X1

        // ---- FFN2: T = X2 + FFN(X2) ----
        for (int c0 = 0; c0 < NBLK; c0 += cb_max) {
            int cb = (NBLK - c0 < cb_max) ? (NBLK - c0) : cb_max;
            ushort* Hl = Hh + (size_t)cb * 128 * DFF;
            gemm_bf16<EP_GELU, RES_NONE, OUT_SPLIT><<<dim3(cb, 8), 256, 0, stream>>>(
                x1h, x1l, 256, nullptr, nullptr, 0, w1t, b1,
                nullptr, nullptr, nullptr, nullptr,
                nullptr, Hh, Hl, DFF, 8, c0, 0);
            gemm_bf16<EP_BIASRES, RES_SPLIT, OUT_SPLIT><<<dim3(cb, 2), 256, 0, stream>>>(
                Hh, Hl, 1024, nullptr, nullptr, 0, w2t, b2,
                nullptr, x1h, x1l, nullptr,
                nullptr, Th, Tl, D, 32, 0, c0);
        }
        // ---- LN2 -> fp32 out ----
        ln_split<1><<<R_TOTAL / 4, 256, 0, stream>>>(Th, Tl, fng, fnb, nullptr, nullptr, outx);
    } else {
        // ---------------- fallback: fp32 path ----------------
        float* m = (float*)d_ws;
        ffn_kernel<16><<<R_TOTAL / 16, 256, 0, stream>>>(feats, aw1, ab1, aw2, ab2, outx);
        ln_kernel<<<R_TOTAL / 4, 256, 0, stream>>>(outx, ng, nb, outx);
        motion_kernel<16><<<R_TOTAL / 16, 128, 0, stream>>>(outx, boxes, masks,
                                                            mw1, mb1, mw2, mb2, mw3, mb3, m);
        fusion_kernel<16><<<R_TOTAL / 16, 256, 0, stream>>>(outx, m, fw1, fb1, fw2, fb2, outx);
        ffn_kernel<16><<<R_TOTAL / 16, 256, 0, stream>>>(outx, w1, b1, w2, b2, outx);
        ln_kernel<<<R_TOTAL / 4, 256, 0, stream>>>(outx, fng, fnb, outx);
    }
    kalman_kernel<<<(NTRACK + 255) / 256, 256, 0, stream>>>(boxes, masks, outst, outcov);
}

// Round 7
// 1082.887 us; speedup vs baseline: 1.3796x; 1.3767x over previous
//
#include <hip/hip_runtime.h>
#include <hip/hip_bf16.h>
#include <math.h>

#define R_TOTAL 64000   // B*G*T*N
#define D 256
#define DFF 1024
#define MDIM 128
#define NB 500
#define TT 16
#define NTRACK 4000
#define NBLK 500        // R_TOTAL / 128

typedef __attribute__((ext_vector_type(8))) short bf8_t;   // 8 bf16
typedef __attribute__((ext_vector_type(4))) float f4_t;    // MFMA acc
typedef __attribute__((ext_vector_type(4))) ushort us4_t;

struct bfpair { ushort h, l; };

__device__ __forceinline__ float gelu_fast(float x) {
    float z = 1.5957691216057308f * (x + 0.044715f * x * x * x);
    return x / (1.0f + __expf(-z));
}
__device__ __forceinline__ float gelu_f(float x) {
    float x3 = x * x * x;
    float t = tanhf(0.7978845608028654f * (x + 0.044715f * x3));
    return 0.5f * x * (1.0f + t);
}
__device__ __forceinline__ float bf2f(ushort u) {
    return __uint_as_float(((uint)u) << 16);
}
__device__ __forceinline__ bfpair f2split(float v) {
    bfpair r;
    __hip_bfloat16 hb = __float2bfloat16(v);
    float hf = __bfloat162float(hb);
    __hip_bfloat16 lb = __float2bfloat16(v - hf);
    r.h = __hip_bfloat16_raw(hb).x;
    r.l = __hip_bfloat16_raw(lb).x;
    return r;
}
__device__ __forceinline__ void split8(float4 a, float4 b, bf8_t& h, bf8_t& l) {
    bfpair s0 = f2split(a.x), s1 = f2split(a.y), s2 = f2split(a.z), s3 = f2split(a.w);
    bfpair s4 = f2split(b.x), s5 = f2split(b.y), s6 = f2split(b.z), s7 = f2split(b.w);
    h[0] = (short)s0.h; h[1] = (short)s1.h; h[2] = (short)s2.h; h[3] = (short)s3.h;
    h[4] = (short)s4.h; h[5] = (short)s5.h; h[6] = (short)s6.h; h[7] = (short)s7.h;
    l[0] = (short)s0.l; l[1] = (short)s1.l; l[2] = (short)s2.l; l[3] = (short)s3.l;
    l[4] = (short)s4.l; l[5] = (short)s5.l; l[6] = (short)s6.l; l[7] = (short)s7.l;
}

// ===========================================================================
// bf16x3-split GEMM. Weight tiles: [colblk][kstep][plane2][n128][k32] bf16.
// LDS A-tile [buf][plane][128][32] with chunk-XOR swizzle -> 2-way banks.
// ASPLIT=1: A sources are pre-split hi/lo planes (pure-copy stage).
// ASPLIT=0: A sources are fp32 (split on the fly in stage).
// ===========================================================================

enum { EP_GELU = 0, EP_RELU = 1, EP_BIAS = 2, EP_BIASRES = 3, EP_MASK = 4 };
enum { RES_NONE = 0, RES_F32 = 1 };
enum { OUT_F32 = 0, OUT_SPLIT = 1 };

template<int MODE, int RES, int OUT, int ASPLIT>
__global__ __launch_bounds__(256, 4)
void gemm_bf16(const void* __restrict__ A1a, const void* __restrict__ A1b, int K1,
               const void* __restrict__ A2a, const void* __restrict__ A2b, int K2w,
               const ushort* __restrict__ Wt,
               const float* __restrict__ bias,
               const float* __restrict__ resF,
               const int* __restrict__ mask,
               float* __restrict__ outF, ushort* __restrict__ outH, ushort* __restrict__ outL,
               int N, int nk)
{
    __shared__ __align__(16) ushort sA[2][2][128][32];   // 32 KB

    const int tid = threadIdx.x;
    const int lane = tid & 63, wid = tid >> 6;
    const int wr = wid >> 1, wc = wid & 1;
    const int colblk = blockIdx.y;
    const int row0 = blockIdx.x * 128;
    const int lm = lane & 15, lg = lane >> 4;

    f4_t acc[4][4];
#pragma unroll
    for (int i = 0; i < 4; ++i)
#pragma unroll
        for (int j = 0; j < 4; ++j) acc[i][j] = (f4_t)0.f;

    auto stage = [&](int ks, int buf) {
        const int k0 = ks * 32;
        const int r0 = tid >> 2;          // 0..63
        const int c  = tid & 3;           // 8-elem k-chunk
        const int cs = (c ^ ((r0 >> 1) & 3)) * 8;
        if (ASPLIT) {
            const ushort *sh, *sl; int stride, kc;
            if (k0 < K1) { sh = (const ushort*)A1a; sl = (const ushort*)A1b; stride = K1; kc = k0; }
            else         { sh = (const ushort*)A2a; sl = (const ushort*)A2b; stride = K2w; kc = k0 - K1; }
            const size_t off0 = (size_t)(row0 + r0) * stride + kc + c * 8;
            const size_t off1 = off0 + (size_t)64 * stride;
            bf8_t h0 = *(const bf8_t*)(sh + off0);
            bf8_t h1 = *(const bf8_t*)(sh + off1);
            bf8_t l0 = *(const bf8_t*)(sl + off0);
            bf8_t l1 = *(const bf8_t*)(sl + off1);
            *(bf8_t*)&sA[buf][0][r0][cs]      = h0;
            *(bf8_t*)&sA[buf][0][r0 + 64][cs] = h1;
            *(bf8_t*)&sA[buf][1][r0][cs]      = l0;
            *(bf8_t*)&sA[buf][1][r0 + 64][cs] = l1;
        } else {
            const float* sf; int stride, kc;
            if (k0 < K1) { sf = (const float*)A1a; stride = K1; kc = k0; }
            else         { sf = (const float*)A2a; stride = K2w; kc = k0 - K1; }
            const int kk = kc + c * 8;
#pragma unroll
            for (int p = 0; p < 2; ++p) {
                int rr = r0 + p * 64;
                const float* s = sf + (size_t)(row0 + rr) * stride + kk;
                float4 v0 = *(const float4*)s;
                float4 v1 = *(const float4*)(s + 4);
                bf8_t h, l;
                split8(v0, v1, h, l);
                *(bf8_t*)&sA[buf][0][rr][cs] = h;
                *(bf8_t*)&sA[buf][1][rr][cs] = l;
            }
        }
    };

    auto compute = [&](int buf, int ks) {
        const ushort* wb = Wt + (((size_t)(colblk * nk + ks)) * 2) * 4096
                              + (wc * 64 + lm) * 32 + lg * 8;
        bf8_t Bh[4], Bl[4];
#pragma unroll
        for (int ct = 0; ct < 4; ++ct) {
            Bh[ct] = *(const bf8_t*)(wb + ct * 512);          // hi plane
            Bl[ct] = *(const bf8_t*)(wb + 4096 + ct * 512);   // lo plane
        }
#pragma unroll
        for (int rt = 0; rt < 4; ++rt) {
            int r = wr * 64 + rt * 16 + lm;
            int cs = (lg ^ ((r >> 1) & 3)) * 8;
            bf8_t Ah = *(const bf8_t*)&sA[buf][0][r][cs];
            bf8_t Al = *(const bf8_t*)&sA[buf][1][r][cs];
#pragma unroll
            for (int ct = 0; ct < 4; ++ct) {
                acc[rt][ct] = __builtin_amdgcn_mfma_f32_16x16x32_bf16(Ah, Bh[ct], acc[rt][ct], 0, 0, 0);
                acc[rt][ct] = __builtin_amdgcn_mfma_f32_16x16x32_bf16(Ah, Bl[ct], acc[rt][ct], 0, 0, 0);
                acc[rt][ct] = __builtin_amdgcn_mfma_f32_16x16x32_bf16(Al, Bh[ct], acc[rt][ct], 0, 0, 0);
            }
        }
    };

    stage(0, 0);
    __syncthreads();
    for (int ks = 0; ks < nk; ++ks) {
        int cur = ks & 1;
        if (ks + 1 < nk) stage(ks + 1, cur ^ 1);
        compute(cur, ks);
        __syncthreads();
    }

    // Epilogue: C/D layout col=lane&15, row=(lane>>4)*4+reg
#pragma unroll
    for (int ct = 0; ct < 4; ++ct) {
        int col = colblk * 128 + wc * 64 + ct * 16 + lm;
        float bv = bias[col];
#pragma unroll
        for (int rt = 0; rt < 4; ++rt) {
#pragma unroll
            for (int rg = 0; rg < 4; ++rg) {
                int row = row0 + wr * 64 + rt * 16 + lg * 4 + rg;
                size_t idx = (size_t)row * N + col;
                float v = acc[rt][ct][rg] + bv;
                if (MODE == EP_GELU)      v = gelu_fast(v);
                else if (MODE == EP_RELU) v = fmaxf(v, 0.f);
                else if (MODE == EP_MASK) v *= (mask[row] != 0) ? 1.0f : 0.0f;
                if (MODE == EP_BIASRES && RES == RES_F32) v += resF[idx];
                if (OUT == OUT_F32) {
                    outF[idx] = v;
                } else {
                    bfpair s = f2split(v);
                    outH[idx] = s.h; outL[idx] = s.l;
                }
            }
        }
    }
}

// --------------------- weight split+tile prep ------------------------------
struct WPrepAll {
    const float* src[9];
    ushort* dst[9];
    int K[9], Kpad[9], logN[9];
    int base[10];
};

__global__ __launch_bounds__(256)
void prep_weights(WPrepAll P)
{
    int idx = blockIdx.x * 256 + threadIdx.x;
    int total = P.base[9];
    for (; idx < total; idx += gridDim.x * 256) {
        int d = 0;
        while (idx >= P.base[d + 1]) ++d;
        int local = idx - P.base[d];
        int N = 1 << P.logN[d];
        int n = local & (N - 1);
        int k = local >> P.logN[d];
        float w = (k < P.K[d]) ? P.src[d][(size_t)k * N + n] : 0.0f;
        bfpair s = f2split(w);
        int colblk = n >> 7, nloc = n & 127;
        int kstep = k >> 5, kk = k & 31;
        int nks = P.Kpad[d] >> 5;
        size_t off = (((size_t)(colblk * nks + kstep)) * 2) * 4096 + (size_t)nloc * 32 + kk;
        P.dst[d][off] = s.h;
        P.dst[d][off + 4096] = s.l;
    }
}

// --------------------- box32f = [boxes(4)|vel(4)|zeros(24)] fp32 -----------
__global__ __launch_bounds__(256)
void prep_box32f(const float* __restrict__ boxes, float* __restrict__ box32)
{
    int idx = blockIdx.x * 256 + threadIdx.x;
    if (idx >= R_TOTAL * 32) return;
    int row = idx >> 5, c = idx & 31;
    float v = 0.0f;
    if (c < 4) {
        v = boxes[(size_t)row * 4 + c];
    } else if (c < 8) {
        int tt = (row / NB) % TT;
        int prev = (tt == 0) ? row : row - NB;
        int j = c - 4;
        v = boxes[(size_t)row * 4 + j] - boxes[(size_t)prev * 4 + j];
    }
    box32[(size_t)row * 32 + c] = v;
}

// --------------------- LayerNorm fp32 (in-place safe) ----------------------
__global__ __launch_bounds__(256)
void ln_kernel(const float* __restrict__ X, const float* __restrict__ g,
               const float* __restrict__ b, float* __restrict__ Y)
{
    const int lane = threadIdx.x & 63;
    const int wave = threadIdx.x >> 6;
    const size_t row = (size_t)blockIdx.x * 4 + wave;
    float4 v = reinterpret_cast<const float4*>(X + row * D)[lane];
    float s = v.x + v.y + v.z + v.w;
#pragma unroll
    for (int m = 32; m >= 1; m >>= 1) s += __shfl_xor(s, m, 64);
    float mu = s * (1.0f / 256.0f);
    float4 d = {v.x - mu, v.y - mu, v.z - mu, v.w - mu};
    float q = d.x * d.x + d.y * d.y + d.z * d.z + d.w * d.w;
#pragma unroll
    for (int m = 32; m >= 1; m >>= 1) q += __shfl_xor(q, m, 64);
    float var = q * (1.0f / 256.0f);
    float sc = 1.0f / sqrtf(var + 1e-5f);
    float4 gv = reinterpret_cast<const float4*>(g)[lane];
    float4 bv = reinterpret_cast<const float4*>(b)[lane];
    float4 o = {d.x * sc * gv.x + bv.x, d.y * sc * gv.y + bv.y,
                d.z * sc * gv.z + bv.z, d.w * sc * gv.w + bv.w};
    reinterpret_cast<float4*>(Y + row * D)[lane] = o;
}

// ---------------------------------------------------------------------------
__global__ __launch_bounds__(256)
void kalman_kernel(const float* __restrict__ boxes, const int* __restrict__ masks,
                   float* __restrict__ st, float* __restrict__ cov)
{
    int i = blockIdx.x * blockDim.x + threadIdx.x;
    if (i >= NTRACK) return;
    int n = i % NB;
    int bg = i / NB;
    size_t rowlast = ((size_t)bg * TT + (TT - 1)) * NB + n;

    float z[4];
#pragma unroll
    for (int j = 0; j < 4; ++j) z[j] = boxes[rowlast * 4 + j];
    int mask = masks[rowlast];

#pragma unroll
    for (int j = 0; j < 4; ++j) st[(size_t)i * 8 + j] = z[j];
#pragma unroll
    for (int j = 4; j < 8; ++j) st[(size_t)i * 8 + j] = 0.0f;

    float C[8][8];
    if (mask != 0) {
#pragma unroll
        for (int a = 0; a < 8; ++a)
#pragma unroll
            for (int b = 0; b < 8; ++b) C[a][b] = (a == b) ? 1.0f : 0.0f;
    } else {
        float Pp[8][8];
#pragma unroll
        for (int a = 0; a < 8; ++a) {
#pragma unroll
            for (int b = 0; b < 8; ++b) {
                float s = 0.f;
#pragma unroll
                for (int k = 0; k < 8; ++k) {
                    float Fa = (a == k ? 1.f : 0.f) + ((a < 4 && k == a + 4) ? 1.f : 0.f);
                    float Fb = (b == k ? 1.f : 0.f) + ((b < 4 && k == b + 4) ? 1.f : 0.f);
                    s = fmaf(Fa, Fb, s);
                }
                Pp[a][b] = s + ((a == b) ? 0.01f : 0.0f);
            }
        }
        float S[4];
#pragma unroll
        for (int j = 0; j < 4; ++j) S[j] = Pp[j][j] + 0.1f;
        float K[8][4];
#pragma unroll
        for (int a = 0; a < 8; ++a)
#pragma unroll
            for (int j = 0; j < 4; ++j) K[a][j] = Pp[a][j] / S[j];
#pragma unroll
        for (int a = 0; a < 8; ++a) {
#pragma unroll
            for (int b = 0; b < 8; ++b) {
                float s = 0.f;
#pragma unroll
                for (int r = 0; r < 4; ++r) s = fmaf(K[a][r], Pp[r][b], s);
                C[a][b] = Pp[a][b] - s;
            }
        }
    }
#pragma unroll
    for (int a = 0; a < 8; ++a)
#pragma unroll
        for (int b = 0; b < 8; ++b) cov[(size_t)i * 64 + a * 8 + b] = C[a][b];
}

// ===========================================================================
// =================  FALLBACK PATH (R1 fp32 kernels)  =======================
// ===========================================================================
template<int BR>
__global__ __launch_bounds__(256)
void ffn_kernel(const float* __restrict__ X,
                const float* __restrict__ W1, const float* __restrict__ B1,
                const float* __restrict__ W2, const float* __restrict__ B2,
                float* __restrict__ Y)
{
    __shared__ float xs[BR][D];
    __shared__ float hs[BR][256];
    const int t = threadIdx.x;
    const int row0 = blockIdx.x * BR;

    for (int i = t; i < BR * D; i += 256) {
        int r = i >> 8, c = i & 255;
        xs[r][c] = X[(size_t)(row0 + r) * D + c];
    }
    __syncthreads();

    float a2[BR];
#pragma unroll
    for (int r = 0; r < BR; ++r) a2[r] = 0.f;

    for (int c = 0; c < DFF / 256; ++c) {
        const int hc = c * 256 + t;
        float a1[BR];
#pragma unroll
        for (int r = 0; r < BR; ++r) a1[r] = 0.f;

        const float* w1p = W1 + hc;
        for (int k = 0; k < D; k += 4) {
            float w0 = w1p[(size_t)(k + 0) * DFF];
            float w1v = w1p[(size_t)(k + 1) * DFF];
            float w2v = w1p[(size_t)(k + 2) * DFF];
            float w3 = w1p[(size_t)(k + 3) * DFF];
#pragma unroll
            for (int r = 0; r < BR; ++r) {
                float4 xv = *reinterpret_cast<const float4*>(&xs[r][k]);
                a1[r] = fmaf(xv.x, w0, a1[r]);
                a1[r] = fmaf(xv.y, w1v, a1[r]);
                a1[r] = fmaf(xv.z, w2v, a1[r]);
                a1[r] = fmaf(xv.w, w3, a1[r]);
            }
        }
        float b1v = B1[hc];
#pragma unroll
        for (int r = 0; r < BR; ++r) hs[r][t] = gelu_f(a1[r] + b1v);
        __syncthreads();

        const float* w2p = W2 + (size_t)c * 256 * D + t;
        for (int k = 0; k < 256; k += 4) {
            float w0 = w2p[(size_t)(k + 0) * D];
            float w1v = w2p[(size_t)(k + 1) * D];
            float w2v = w2p[(size_t)(k + 2) * D];
            float w3 = w2p[(size_t)(k + 3) * D];
#pragma unroll
            for (int r = 0; r < BR; ++r) {
                float4 hv = *reinterpret_cast<const float4*>(&hs[r][k]);
                a2[r] = fmaf(hv.x, w0, a2[r]);
                a2[r] = fmaf(hv.y, w1v, a2[r]);
                a2[r] = fmaf(hv.z, w2v, a2[r]);
                a2[r] = fmaf(hv.w, w3, a2[r]);
            }
        }
        __syncthreads();
    }

    float b2v = B2[t];
#pragma unroll
    for (int r = 0; r < BR; ++r) {
        Y[(size_t)(row0 + r) * D + t] = xs[r][t] + a2[r] + b2v;
    }
}

template<int BR>
__global__ __launch_bounds__(128)
void motion_kernel(const float* __restrict__ x1, const float* __restrict__ boxes,
                   const int* __restrict__ masks,
                   const float* __restrict__ MW1, const float* __restrict__ MB1,
                   const float* __restrict__ MW2, const float* __restrict__ MB2,
                   const float* __restrict__ MW3, const float* __restrict__ MB3,
                   float* __restrict__ Mout)
{
    __shared__ float ins[BR][264];
    __shared__ float h1[BR][MDIM];
    __shared__ float h2[BR][MDIM];
    const int t = threadIdx.x;
    const int row0 = blockIdx.x * BR;

    for (int i = t; i < BR * 264; i += 128) {
        int r = i / 264, c = i % 264;
        int row = row0 + r;
        float v;
        if (c < 256) {
            v = x1[(size_t)row * D + c];
        } else if (c < 260) {
            v = boxes[(size_t)row * 4 + (c - 256)];
        } else {
            int tt = (row / NB) % TT;
            int prev = (tt == 0) ? row : row - NB;
            int j = c - 260;
            v = boxes[(size_t)row * 4 + j] - boxes[(size_t)prev * 4 + j];
        }
        ins[r][c] = v;
    }
    __syncthreads();

    float a[BR];
#pragma unroll
    for (int r = 0; r < BR; ++r) a[r] = 0.f;
    for (int k = 0; k < 264; k += 4) {
        float w0 = MW1[(size_t)(k + 0) * MDIM + t];
        float w1 = MW1[(size_t)(k + 1) * MDIM + t];
        float w2 = MW1[(size_t)(k + 2) * MDIM + t];
        float w3 = MW1[(size_t)(k + 3) * MDIM + t];
#pragma unroll
        for (int r = 0; r < BR; ++r) {
            float4 xv = *reinterpret_cast<const float4*>(&ins[r][k]);
            a[r] = fmaf(xv.x, w0, a[r]);
            a[r] = fmaf(xv.y, w1, a[r]);
            a[r] = fmaf(xv.z, w2, a[r]);
            a[r] = fmaf(xv.w, w3, a[r]);
        }
    }
    float bb1 = MB1[t];
#pragma unroll
    for (int r = 0; r < BR; ++r) h1[r][t] = gelu_f(a[r] + bb1);
    __syncthreads();

#pragma unroll
    for (int r = 0; r < BR; ++r) a[r] = 0.f;
    for (int k = 0; k < MDIM; k += 4) {
        float w0 = MW2[(size_t)(k + 0) * MDIM + t];
        float w1 = MW2[(size_t)(k + 1) * MDIM + t];
        float w2 = MW2[(size_t)(k + 2) * MDIM + t];
        float w3 = MW2[(size_t)(k + 3) * MDIM + t];
#pragma unroll
        for (int r = 0; r < BR; ++r) {
            float4 xv = *reinterpret_cast<const float4*>(&h1[r][k]);
            a[r] = fmaf(xv.x, w0, a[r]);
            a[r] = fmaf(xv.y, w1, a[r]);
            a[r] = fmaf(xv.z, w2, a[r]);
            a[r] = fmaf(xv.w, w3, a[r]);
        }
    }
    float bb2 = MB2[t];
#pragma unroll
    for (int r = 0; r < BR; ++r) h2[r][t] = gelu_f(a[r] + bb2);
    __syncthreads();

#pragma unroll
    for (int r = 0; r < BR; ++r) a[r] = 0.f;
    for (int k = 0; k < MDIM; k += 4) {
        float w0 = MW3[(size_t)(k + 0) * MDIM + t];
        float w1 = MW3[(size_t)(k + 1) * MDIM + t];
        float w2 = MW3[(size_t)(k + 2) * MDIM + t];
        float w3 = MW3[(size_t)(k + 3) * MDIM + t];
#pragma unroll
        for (int r = 0; r < BR; ++r) {
            float4 xv = *reinterpret_cast<const float4*>(&h2[r][k]);
            a[r] = fmaf(xv.x, w0, a[r]);
            a[r] = fmaf(xv.y, w1, a[r]);
            a[r] = fmaf(xv.z, w2, a[r]);
            a[r] = fmaf(xv.w, w3, a[r]);
        }
    }
    float bb3 = MB3[t];
#pragma unroll
    for (int r = 0; r < BR; ++r) {
        float mf = (masks[row0 + r] != 0) ? 1.0f : 0.0f;
        Mout[(size_t)(row0 + r) * MDIM + t] = (a[r] + bb3) * mf;
    }
}

template<int BR>
__global__ __launch_bounds__(256)
void fusion_kernel(const float* __restrict__ x1, const float* __restrict__ m,
                   const float* __restrict__ FW1, const float* __restrict__ FB1,
                   const float* __restrict__ FW2, const float* __restrict__ FB2,
                   float* __restrict__ Y)
{
    __shared__ float fin[BR][384];
    __shared__ float h[BR][256];
    const int t = threadIdx.x;
    const int row0 = blockIdx.x * BR;

    for (int i = t; i < BR * 384; i += 256) {
        int r = i / 384, c = i % 384;
        int row = row0 + r;
        fin[r][c] = (c < 256) ? x1[(size_t)row * D + c]
                              : m[(size_t)row * MDIM + (c - 256)];
    }
    __syncthreads();

    float a[BR];
#pragma unroll
    for (int r = 0; r < BR; ++r) a[r] = 0.f;
    for (int k = 0; k < 384; k += 4) {
        float w0 = FW1[(size_t)(k + 0) * D + t];
        float w1 = FW1[(size_t)(k + 1) * D + t];
        float w2 = FW1[(size_t)(k + 2) * D + t];
        float w3 = FW1[(size_t)(k + 3) * D + t];
#pragma unroll
        for (int r = 0; r < BR; ++r) {
            float4 xv = *reinterpret_cast<const float4*>(&fin[r][k]);
            a[r] = fmaf(xv.x, w0, a[r]);
            a[r] = fmaf(xv.y, w1, a[r]);
            a[r] = fmaf(xv.z, w2, a[r]);
            a[r] = fmaf(xv.w, w3, a[r]);
        }
    }
    float fb = FB1[t];
#pragma unroll
    for (int r = 0; r < BR; ++r) h[r][t] = fmaxf(a[r] + fb, 0.f);
    __syncthreads();

    float a2[BR];
#pragma unroll
    for (int r = 0; r < BR; ++r) a2[r] = 0.f;
    for (int k = 0; k < D; k += 4) {
        float w0 = FW2[(size_t)(k + 0) * D + t];
        float w1 = FW2[(size_t)(k + 1) * D + t];
        float w2 = FW2[(size_t)(k + 2) * D + t];
        float w3 = FW2[(size_t)(k + 3) * D + t];
#pragma unroll
        for (int r = 0; r < BR; ++r) {
            float4 hv = *reinterpret_cast<const float4*>(&h[r][k]);
            a2[r] = fmaf(hv.x, w0, a2[r]);
            a2[r] = fmaf(hv.y, w1, a2[r]);
            a2[r] = fmaf(hv.z, w2, a2[r]);
            a2[r] = fmaf(hv.w, w3, a2[r]);
        }
    }
    float fb2v = FB2[t];
#pragma unroll
    for (int r = 0; r < BR; ++r) {
        Y[(size_t)(row0 + r) * D + t] = a2[r] + fb2v;
    }
}

// ===========================================================================
extern "C" void kernel_launch(void* const* d_in, const int* in_sizes, int n_in,
                              void* d_out, int out_size, void* d_ws, size_t ws_size,
                              hipStream_t stream)
{
    const float* feats = (const float*)d_in[0];
    const float* boxes = (const float*)d_in[1];
    const int*   masks = (const int*)d_in[2];
    const float* aw1 = (const float*)d_in[3];
    const float* ab1 = (const float*)d_in[4];
    const float* aw2 = (const float*)d_in[5];
    const float* ab2 = (const float*)d_in[6];
    const float* ng  = (const float*)d_in[7];
    const float* nb  = (const float*)d_in[8];
    const float* mw1 = (const float*)d_in[9];
    const float* mb1 = (const float*)d_in[10];
    const float* mw2 = (const float*)d_in[11];
    const float* mb2 = (const float*)d_in[12];
    const float* mw3 = (const float*)d_in[13];
    const float* mb3 = (const float*)d_in[14];
    const float* fw1 = (const float*)d_in[15];
    const float* fb1 = (const float*)d_in[16];
    const float* fw2 = (const float*)d_in[17];
    const float* fb2 = (const float*)d_in[18];
    const float* w1  = (const float*)d_in[19];
    const float* b1  = (const float*)d_in[20];
    const float* w2  = (const float*)d_in[21];
    const float* b2  = (const float*)d_in[22];
    const float* fng = (const float*)d_in[23];
    const float* fnb = (const float*)d_in[24];

    float* outx   = (float*)d_out;     // fp32 activation buffer (X / T)
    float* outst  = outx + (size_t)R_TOTAL * D;
    float* outcov = outst + (size_t)NTRACK * 8;

    // ---- ws layout: weights (5.13 MB) | H region (262.14 MB) ----
    char* p = (char*)d_ws;
    ushort* aw1t = (ushort*)p;  p += 1048576;
    ushort* aw2t = (ushort*)p;  p += 1048576;
    ushort* w1t  = (ushort*)p;  p += 1048576;
    ushort* w2t  = (ushort*)p;  p += 1048576;
    ushort* fw1t = (ushort*)p;  p += 393216;
    ushort* fw2t = (ushort*)p;  p += 262144;
    ushort* mw1t = (ushort*)p;  p += 147456;
    ushort* mw2t = (ushort*)p;  p += 65536;
    ushort* mw3t = (ushort*)p;  p += 65536;
    char* Hr = p;
    const size_t H_BYTES = (size_t)R_TOTAL * DFF * 4;   // 262,144,000 (hi+lo planes)
    size_t need = (size_t)(Hr - (char*)d_ws) + H_BYTES;

    // H planes (FFN hidden, full R)
    ushort* Hh = (ushort*)Hr;
    ushort* Hl = Hh + (size_t)R_TOTAL * DFF;
    // aliases inside H region (dead between FFN_a-G2 and FFN2-G1)
    float*  box32f = (float*)Hr;                                  // 8.2 MB
    ushort* h1h = (ushort*)(Hr + ((size_t)16 << 20));             // 16.4 MB
    ushort* h1l = h1h + (size_t)R_TOTAL * MDIM;                   // +16.4
    ushort* h2h = (ushort*)(Hr + ((size_t)56 << 20));
    ushort* h2l = h2h + (size_t)R_TOTAL * MDIM;
    float*  m1f = (float*)(Hr + ((size_t)96 << 20));              // 32.8 MB fp32
    ushort* hfh = (ushort*)(Hr + ((size_t)140 << 20));            // 32.8 MB
    ushort* hfl = hfh + (size_t)R_TOTAL * D;                      // +32.8

    if (ws_size >= need) {
        // ---------------- fast path: full-grid bf16x3 MFMA ----------------
        WPrepAll P;
        const float* srcs[9] = {aw1, aw2, w1, w2, fw1, fw2, mw1, mw2, mw3};
        ushort* dsts[9] = {aw1t, aw2t, w1t, w2t, fw1t, fw2t, mw1t, mw2t, mw3t};
        int Ks[9]    = {256, 1024, 256, 1024, 384, 256, 264, 128, 128};
        int Kpads[9] = {256, 1024, 256, 1024, 384, 256, 288, 128, 128};
        int logNs[9] = {10, 8, 10, 8, 8, 8, 7, 7, 7};
        int base = 0;
        for (int i = 0; i < 9; ++i) {
            P.src[i] = srcs[i]; P.dst[i] = dsts[i];
            P.K[i] = Ks[i]; P.Kpad[i] = Kpads[i]; P.logN[i] = logNs[i];
            P.base[i] = base;
            base += Kpads[i] << logNs[i];
        }
        P.base[9] = base;
        prep_weights<<<(base + 255) / 256, 256, 0, stream>>>(P);

        // ---- FFN_a: H = gelu(feats@aw1+ab1); T = H@aw2+ab2+feats -> outx ----
        gemm_bf16<EP_GELU, RES_NONE, OUT_SPLIT, 0><<<dim3(NBLK, 8), 256, 0, stream>>>(
            feats, nullptr, 256, nullptr, nullptr, 0, aw1t, ab1,
            nullptr, nullptr, nullptr, Hh, Hl, DFF, 8);
        gemm_bf16<EP_BIASRES, RES_F32, OUT_F32, 1><<<dim3(NBLK, 2), 256, 0, stream>>>(
            Hh, Hl, 1024, nullptr, nullptr, 0, aw2t, ab2,
            feats, nullptr, outx, nullptr, nullptr, D, 32);
        // ---- LN1 in-place on outx ----
        ln_kernel<<<R_TOTAL / 4, 256, 0, stream>>>(outx, ng, nb, outx);
        // box table (H region now dead)
        prep_box32f<<<(R_TOTAL * 32 + 255) / 256, 256, 0, stream>>>(boxes, box32f);

        // ---- motion MLP ----
        gemm_bf16<EP_GELU, RES_NONE, OUT_SPLIT, 0><<<dim3(NBLK, 1), 256, 0, stream>>>(
            outx, nullptr, 256, box32f, nullptr, 32, mw1t, mb1,
            nullptr, nullptr, nullptr, h1h, h1l, MDIM, 9);
        gemm_bf16<EP_GELU, RES_NONE, OUT_SPLIT, 1><<<dim3(NBLK, 1), 256, 0, stream>>>(
            h1h, h1l, 128, nullptr, nullptr, 0, mw2t, mb2,
            nullptr, nullptr, nullptr, h2h, h2l, MDIM, 4);
        gemm_bf16<EP_MASK, RES_NONE, OUT_F32, 1><<<dim3(NBLK, 1), 256, 0, stream>>>(
            h2h, h2l, 128, nullptr, nullptr, 0, mw3t, mb3,
            nullptr, masks, m1f, nullptr, nullptr, MDIM, 4);

        // ---- fusion ----
        gemm_bf16<EP_RELU, RES_NONE, OUT_SPLIT, 0><<<dim3(NBLK, 2), 256, 0, stream>>>(
            outx, nullptr, 256, m1f, nullptr, 128, fw1t, fb1,
            nullptr, nullptr, nullptr, hfh, hfl, D, 12);
        gemm_bf16<EP_BIAS, RES_NONE, OUT_F32, 1><<<dim3(NBLK, 2), 256, 0, stream>>>(
            hfh, hfl, 256, nullptr, nullptr, 0, fw2t, fb2,
            nullptr, nullptr, outx, nullptr, nullptr, D, 8);

        // ---- FFN2: H = gelu(X2@w1+b1); T = H@w2+b2+X2 -> outx ----
        gemm_bf16<EP_GELU, RES_NONE, OUT_SPLIT, 0><<<dim3(NBLK, 8), 256, 0, stream>>>(
            outx, nullptr, 256, nullptr, nullptr, 0, w1t, b1,
            nullptr, nullptr, nullptr, Hh, Hl, DFF, 8);
        gemm_bf16<EP_BIASRES, RES_F32, OUT_F32, 1><<<dim3(NBLK, 2), 256, 0, stream>>>(
            Hh, Hl, 1024, nullptr, nullptr, 0, w2t, b2,
            outx, nullptr, outx, nullptr, nullptr, D, 32);
        // ---- LN2 in-place ----
        ln_kernel<<<R_TOTAL / 4, 256, 0, stream>>>(outx, fng, fnb, outx);
    } else {
        // ---------------- fallback: fp32 path ----------------
        float* m = (float*)d_ws;
        ffn_kernel<16><<<R_TOTAL / 16, 256, 0, stream>>>(feats, aw1, ab1, aw2, ab2, outx);
        ln_kernel<<<R_TOTAL / 4, 256, 0, stream>>>(outx, ng, nb, outx);
        motion_kernel<16><<<R_TOTAL / 16, 128, 0, stream>>>(outx, boxes, masks,
                                                            mw1, mb1, mw2, mb2, mw3, mb3, m);
        fusion_kernel<16><<<R_TOTAL / 16, 256, 0, stream>>>(outx, m, fw1, fb1, fw2, fb2, outx);
        ffn_kernel<16><<<R_TOTAL / 16, 256, 0, stream>>>(outx, w1, b1, w2, b2, outx);
        ln_kernel<<<R_TOTAL / 4, 256, 0, stream>>>(outx, fng, fnb, outx);
    }
    kalman_kernel<<<(NTRACK + 255) / 256, 256, 0, stream>>>(boxes, masks, outst, outcov);
}